// Round 2
// baseline (739.391 us; speedup 1.0000x reference)
//
#include <hip/hip_runtime.h>
#include <hip/hip_bf16.h>

typedef unsigned short u16;
typedef unsigned int u32;
typedef __bf16 bf16x8 __attribute__((ext_vector_type(8)));
typedef float f32x4 __attribute__((ext_vector_type(4)));

// ---------- helpers ----------
__device__ __forceinline__ u16 f2bf(float f) {
  union { float f; unsigned u; } v; v.f = f;
  unsigned r = v.u + 0x7fffu + ((v.u >> 16) & 1u);   // RNE
  return (u16)(r >> 16);
}

__device__ __forceinline__ f32x4 mfma16(bf16x8 a, bf16x8 b, f32x4 c) {
  return __builtin_amdgcn_mfma_f32_16x16x32_bf16(a, b, c, 0, 0, 0);
}

// async global->LDS, 16B per lane; LDS dest = wave-uniform base + lane*16
__device__ __forceinline__ void gl_lds16(const u16* g, u16* l) {
  __builtin_amdgcn_global_load_lds(
      (const __attribute__((address_space(1))) u32*)g,
      (__attribute__((address_space(3))) u32*)l, 16, 0, 0);
}

// ---------- bf16 conversion kernels ----------
__global__ __launch_bounds__(256) void cvt_x_kernel(const float* __restrict__ x, u16* __restrict__ xb) {
  size_t i = (size_t)blockIdx.x * 256 + threadIdx.x;     // 524288 float4's
  float4 v = reinterpret_cast<const float4*>(x)[i];
  unsigned long long pk = (unsigned long long)f2bf(v.x) |
                          ((unsigned long long)f2bf(v.y) << 16) |
                          ((unsigned long long)f2bf(v.z) << 32) |
                          ((unsigned long long)f2bf(v.w) << 48);
  *reinterpret_cast<unsigned long long*>(xb + i * 4) = pk;
}

__global__ __launch_bounds__(256) void cvt_w_kernel(
    const float* __restrict__ qW, const float* __restrict__ kW,
    const float* __restrict__ vW, const float* __restrict__ oW,
    u16* __restrict__ wb_qkv, u16* __restrict__ wb_o, int e0, int G) {
  size_t nqkv4 = (size_t)G * 3 * 262144;                 // float4 units
  size_t total = nqkv4 + (size_t)G * 262144;
  for (size_t i = (size_t)blockIdx.x * 256 + threadIdx.x; i < total;
       i += (size_t)gridDim.x * 256) {
    const float* src; u16* dst;
    if (i < nqkv4) {
      size_t elem = i * 4;
      size_t blk = elem >> 20;              // e_local*3 + type
      size_t el = blk / 3, ty = blk % 3;
      const float* W = (ty == 0 ? qW : (ty == 1 ? kW : vW));
      src = W + (size_t)(e0 + el) * 1048576 + (elem & 1048575);
      dst = wb_qkv + elem;
    } else {
      size_t elem = (i - nqkv4) * 4;
      size_t el = elem >> 20;
      src = oW + (size_t)(e0 + el) * 1048576 + (elem & 1048575);
      dst = wb_o + elem;
    }
    float4 v = *reinterpret_cast<const float4*>(src);
    unsigned long long pk = (unsigned long long)f2bf(v.x) |
                            ((unsigned long long)f2bf(v.y) << 16) |
                            ((unsigned long long)f2bf(v.z) << 32) |
                            ((unsigned long long)f2bf(v.w) << 48);
    *reinterpret_cast<unsigned long long*>(dst) = pk;
  }
}

// ---------- router (fp32 for exact top-2 selection) ----------
__global__ __launch_bounds__(256) void router_gemm1(
    const float* __restrict__ x, const float* __restrict__ rW1,
    const float* __restrict__ rb1, float* __restrict__ hbuf) {
  __shared__ float aT[16][72];
  __shared__ float bT[16][72];
  int t = threadIdx.x;
  int tx = t & 15, ty = t >> 4;
  int m0 = blockIdx.x * 64, n0 = blockIdx.y * 64;
  float acc[4][4];
#pragma unroll
  for (int i = 0; i < 4; ++i)
#pragma unroll
    for (int j = 0; j < 4; ++j) acc[i][j] = 0.f;
  const float* Ab = x + (size_t)m0 * 1024;
  const float* Bb = rW1 + (size_t)n0 * 1024;
  int r = t >> 2, c4 = (t & 3) * 4;
  for (int k0 = 0; k0 < 1024; k0 += 16) {
    float4 av = *reinterpret_cast<const float4*>(Ab + (size_t)r * 1024 + k0 + c4);
    float4 bv = *reinterpret_cast<const float4*>(Bb + (size_t)r * 1024 + k0 + c4);
    aT[c4 + 0][r] = av.x; aT[c4 + 1][r] = av.y; aT[c4 + 2][r] = av.z; aT[c4 + 3][r] = av.w;
    bT[c4 + 0][r] = bv.x; bT[c4 + 1][r] = bv.y; bT[c4 + 2][r] = bv.z; bT[c4 + 3][r] = bv.w;
    __syncthreads();
#pragma unroll
    for (int kk = 0; kk < 16; ++kk) {
      float4 a = *reinterpret_cast<const float4*>(&aT[kk][ty * 4]);
      float4 b = *reinterpret_cast<const float4*>(&bT[kk][tx * 4]);
      float aa[4] = {a.x, a.y, a.z, a.w};
      float bb[4] = {b.x, b.y, b.z, b.w};
#pragma unroll
      for (int i = 0; i < 4; ++i)
#pragma unroll
        for (int j = 0; j < 4; ++j) acc[i][j] += aa[i] * bb[j];
    }
    __syncthreads();
  }
#pragma unroll
  for (int i = 0; i < 4; ++i) {
    int row = m0 + ty * 4 + i;
#pragma unroll
    for (int j = 0; j < 4; ++j) {
      int col = n0 + tx * 4 + j;
      hbuf[(size_t)row * 512 + col] = acc[i][j] + rb1[col];
    }
  }
}

__global__ __launch_bounds__(64) void router_finish(
    const float* __restrict__ hbuf, const float* __restrict__ ln_g,
    const float* __restrict__ ln_b, const float* __restrict__ rW2,
    const float* __restrict__ rb2, float* __restrict__ gates) {
  int tok = blockIdx.x, lane = threadIdx.x;
  const float* hr = hbuf + (size_t)tok * 512;
  float4 v0 = *reinterpret_cast<const float4*>(hr + lane * 8);
  float4 v1 = *reinterpret_cast<const float4*>(hr + lane * 8 + 4);
  float hv[8] = {v0.x, v0.y, v0.z, v0.w, v1.x, v1.y, v1.z, v1.w};
  float s = 0.f;
#pragma unroll
  for (int j = 0; j < 8; ++j) s += hv[j];
#pragma unroll
  for (int m = 1; m < 64; m <<= 1) s += __shfl_xor(s, m);
  float mu = s * (1.0f / 512.0f);
  float s2 = 0.f;
#pragma unroll
  for (int j = 0; j < 8; ++j) { float d = hv[j] - mu; s2 += d * d; }
#pragma unroll
  for (int m = 1; m < 64; m <<= 1) s2 += __shfl_xor(s2, m);
  float rstd = 1.0f / sqrtf(s2 * (1.0f / 512.0f) + 1e-5f);
#pragma unroll
  for (int j = 0; j < 8; ++j) {
    float tv = (hv[j] - mu) * rstd * ln_g[lane * 8 + j] + ln_b[lane * 8 + j];
    hv[j] = fmaxf(tv, 0.0f);
  }
  float logit[8];
#pragma unroll
  for (int n = 0; n < 8; ++n) {
    const float* wr = rW2 + (size_t)n * 512 + lane * 8;
    float p = 0.f;
#pragma unroll
    for (int j = 0; j < 8; ++j) p += hv[j] * wr[j];
#pragma unroll
    for (int m = 1; m < 64; m <<= 1) p += __shfl_xor(p, m);
    logit[n] = p + rb2[n];
  }
  int i1 = 0; float l1 = logit[0];
#pragma unroll
  for (int n = 1; n < 8; ++n) if (logit[n] > l1) { l1 = logit[n]; i1 = n; }
  int i2 = -1; float l2 = -3.4e38f;
#pragma unroll
  for (int n = 0; n < 8; ++n) if (n != i1 && logit[n] > l2) { l2 = logit[n]; i2 = n; }
  float e2 = __expf(l2 - l1);
  float g1 = 1.0f / (1.0f + e2);
  float g2 = e2 * g1;
  if (lane < 8) gates[(size_t)lane * 2048 + tok] = (lane == i1) ? g1 : ((lane == i2) ? g2 : 0.0f);
}

// out[t][n] = sum_e gates[e][t] * ob[e][n]   (bias term; also zero-inits out)
__global__ __launch_bounds__(256) void init_out_kernel(
    const float* __restrict__ gates, const float* __restrict__ ob, float* __restrict__ out) {
  for (size_t i = (size_t)blockIdx.x * 256 + threadIdx.x; i < 524288;
       i += (size_t)gridDim.x * 256) {
    int tok = (int)(i >> 8);
    int c4 = (int)(i & 255) * 4;
    float4 acc = {0.f, 0.f, 0.f, 0.f};
#pragma unroll
    for (int e = 0; e < 8; ++e) {
      float g = gates[(size_t)e * 2048 + tok];
      float4 bv = *reinterpret_cast<const float4*>(ob + (size_t)e * 1024 + c4);
      acc.x += g * bv.x; acc.y += g * bv.y; acc.z += g * bv.z; acc.w += g * bv.w;
    }
    *reinterpret_cast<float4*>(out + (size_t)tok * 1024 + c4) = acc;
  }
}

// ---------- 128x128 bf16 MFMA GEMM mainloop, m97-style global_load_lds ----------
// LDS(row, c) = Global(row, c ^ (row&7)) via inverse-swizzled per-lane SOURCE.
__device__ __forceinline__ void gemm_mainloop(
    const u16* __restrict__ A, int lda, const u16* __restrict__ B, int ldb,
    int K, u16* aL, u16* bL, f32x4 acc[4][4]) {
  const int t = threadIdx.x;
  const int w = t >> 6, lane = t & 63;
  const int wm = (w >> 1) * 64, wn = (w & 1) * 64;
  const int lr = lane & 15, lg = lane >> 4;
  const int rloc = lane >> 3, cloc = lane & 7;
  for (int k0 = 0; k0 < K; k0 += 64) {
#pragma unroll
    for (int u = 0; u < 4; ++u) {
      int row = 32 * w + 8 * u + rloc;
      int sc = cloc ^ (row & 7);
      gl_lds16(A + (size_t)row * lda + k0 + sc * 8, aL + (32 * w + 8 * u) * 64);
      gl_lds16(B + (size_t)row * ldb + k0 + sc * 8, bL + (32 * w + 8 * u) * 64);
    }
    __syncthreads();   // drains vmcnt(0) -> gload data resident
#pragma unroll
    for (int kk = 0; kk < 2; ++kk) {
      bf16x8 af[4], bfr[4];
#pragma unroll
      for (int i = 0; i < 4; ++i) {
        int ra = wm + i * 16 + lr;
        af[i] = *reinterpret_cast<const bf16x8*>(aL + ra * 64 + (((kk * 4 + lg) ^ (ra & 7)) << 3));
        int rb = wn + i * 16 + lr;
        bfr[i] = *reinterpret_cast<const bf16x8*>(bL + rb * 64 + (((kk * 4 + lg) ^ (rb & 7)) << 3));
      }
#pragma unroll
      for (int mi = 0; mi < 4; ++mi)
#pragma unroll
        for (int ni = 0; ni < 4; ++ni)
          acc[mi][ni] = mfma16(af[mi], bfr[ni], acc[mi][ni]);
    }
    __syncthreads();
  }
}

// ---------- QKV projection GEMM ----------
__global__ __launch_bounds__(256) void qkv_gemm_kernel(
    const u16* __restrict__ xb, const u16* __restrict__ wb_qkv,
    const float* __restrict__ qb, const float* __restrict__ kb, const float* __restrict__ vb,
    u16* __restrict__ qkv, int e0, int G) {
  __shared__ u16 lds[16384];
  int nwg = G * 384, q = nwg >> 3;
  int orig = blockIdx.x;
  int wgid = (orig & 7) * q + (orig >> 3);     // XCD-bijective swizzle (nwg%8==0)
  int nblk = wgid >> 4, mblk = wgid & 15;
  const u16* A = xb + (size_t)mblk * 128 * 1024;
  const u16* B = wb_qkv + (size_t)nblk * 128 * 1024;
  f32x4 acc[4][4];
#pragma unroll
  for (int i = 0; i < 4; ++i)
#pragma unroll
    for (int j = 0; j < 4; ++j) { f32x4 z = {0.f, 0.f, 0.f, 0.f}; acc[i][j] = z; }
  gemm_mainloop(A, 1024, B, 1024, 1024, lds, lds + 8192, acc);

  const int t = threadIdx.x, w = t >> 6, lane = t & 63;
  const int wm = (w >> 1) * 64, wn = (w & 1) * 64;
  const int lr = lane & 15, lg = lane >> 4;
  int n0 = nblk * 128;
  int etl = n0 >> 10;                 // e_local*3 + type
  int el = etl / 3, ty = etl % 3;
  const float* biasArr = (ty == 0 ? qb : (ty == 1 ? kb : vb)) + (size_t)(e0 + el) * 1024;
  int ncol0 = n0 & 1023;
  u16* Cb = qkv + ((size_t)etl * 2048 + (size_t)mblk * 128) * 1024 + ncol0;
#pragma unroll
  for (int ni = 0; ni < 4; ++ni) {
    int lcol = wn + ni * 16 + lr;
    float bv = biasArr[ncol0 + lcol];
#pragma unroll
    for (int mi = 0; mi < 4; ++mi)
#pragma unroll
      for (int rg = 0; rg < 4; ++rg) {
        int lrow = wm + mi * 16 + lg * 4 + rg;
        Cb[(size_t)lrow * 1024 + lcol] = f2bf(acc[mi][ni][rg] + bv);
      }
  }
}

// ---------- flash attention, pipelined (K via gload_lds, V pair-packed, dbuf) ----------
__global__ __launch_bounds__(256) void attn_kernel(
    const u16* __restrict__ qkv, const float* __restrict__ gates,
    u16* __restrict__ o_all, int e0, int G) {
  __shared__ u16 Kl[2][4096];      // [buf][row 64][col 64] linear; reads XOR-swizzled
  __shared__ u32 Vtl[2][2048];     // [buf][d 64][s2 32] u32 (bf16 pair), chunk-swizzled
  __shared__ u16 Pl[4096];         // per-wave 1024
  int nwg = G * 512, qsw = nwg >> 3;
  int orig = blockIdx.x;
  int wgid = (orig & 7) * qsw + (orig >> 3);
  int qt = wgid & 15;
  int h = (wgid >> 4) & 15;
  int b = (wgid >> 8) & 1;
  int el = wgid >> 9;
  const size_t mat = (size_t)2048 * 1024;
  const u16* Q  = qkv + (size_t)(el * 3 + 0) * mat + (size_t)b * 1048576 + h * 64;
  const u16* Kg = qkv + (size_t)(el * 3 + 1) * mat + (size_t)b * 1048576 + h * 64;
  const u16* Vg = qkv + (size_t)(el * 3 + 2) * mat + (size_t)b * 1048576 + h * 64;
  u16* Og = o_all + (size_t)el * mat + (size_t)b * 1048576 + h * 64;
  const float* gvec = gates + (size_t)(e0 + el) * 2048 + (size_t)b * 1024;
  const int t = threadIdx.x, w = t >> 6, lane = t & 63;
  const int lr = lane & 15, lg = lane >> 4;
  const int q0 = qt * 64 + w * 16;
  // K staging ids (gload): wave w covers rows 16w..16w+15, 2 rounds of 8
  const int krow_l = (lane >> 3), kc = lane & 7;
  // V staging ids: row-pairs
  const int sr2 = (t >> 3) * 2, sc3 = t & 7;

  bf16x8 qa[2];
#pragma unroll
  for (int kk = 0; kk < 2; ++kk)
    qa[kk] = *reinterpret_cast<const bf16x8*>(Q + (size_t)(q0 + lr) * 1024 + kk * 32 + lg * 8);

  f32x4 oacc[4];
  float mrun[4], lsum[4];
#pragma unroll
  for (int i = 0; i < 4; ++i) {
    f32x4 z = {0.f, 0.f, 0.f, 0.f}; oacc[i] = z; mrun[i] = -3.4e38f; lsum[i] = 0.f;
  }

  // prologue: stage K(0), load V(0) regs
  int4 vreg[2][2];
#pragma unroll
  for (int r = 0; r < 2; ++r) {
    int row = 16 * w + 8 * r + krow_l;
    gl_lds16(Kg + (size_t)row * 1024 + (kc ^ (row & 7)) * 8, &Kl[0][(16 * w + 8 * r) * 64]);
  }
  vreg[0][0] = *reinterpret_cast<const int4*>(Vg + (size_t)sr2 * 1024 + sc3 * 8);
  vreg[0][1] = *reinterpret_cast<const int4*>(Vg + (size_t)(sr2 + 1) * 1024 + sc3 * 8);

#pragma unroll 2
  for (int it = 0; it < 16; ++it) {
    const int cur = it & 1;
    // ---- write V^T(it) pair-packed (compiler waits the int4 loads) ----
    {
      const u16* v0 = reinterpret_cast<const u16*>(&vreg[cur][0]);
      const u16* v1 = reinterpret_cast<const u16*>(&vreg[cur][1]);
      int s2 = sr2 >> 1;
#pragma unroll
      for (int j = 0; j < 8; ++j) {
        int jj = (j + sc3) & 7;                 // rotate: conflict-free writes
        int d = sc3 * 8 + jj;
        u32 val = (u32)v0[jj] | ((u32)v1[jj] << 16);
        Vtl[cur][d * 32 + (((s2 >> 2) ^ (d & 7)) << 2) + (s2 & 3)] = val;
      }
    }
    __syncthreads();   // drains gload K(it) + V^T writes; all buffers[cur] ready
    // ---- prefetch next tile (hidden under compute) ----
    if (it + 1 < 16) {
      int kv1 = (it + 1) * 64;
#pragma unroll
      for (int r = 0; r < 2; ++r) {
        int row = 16 * w + 8 * r + krow_l;
        gl_lds16(Kg + (size_t)(kv1 + row) * 1024 + (kc ^ (row & 7)) * 8,
                 &Kl[cur ^ 1][(16 * w + 8 * r) * 64]);
      }
      vreg[cur ^ 1][0] = *reinterpret_cast<const int4*>(Vg + (size_t)(kv1 + sr2) * 1024 + sc3 * 8);
      vreg[cur ^ 1][1] = *reinterpret_cast<const int4*>(Vg + (size_t)(kv1 + sr2 + 1) * 1024 + sc3 * 8);
    }
    // ---- QK^T ----
    f32x4 sv[4];
    __builtin_amdgcn_s_setprio(1);
#pragma unroll
    for (int nt = 0; nt < 4; ++nt) {
      f32x4 z = {0.f, 0.f, 0.f, 0.f};
#pragma unroll
      for (int kk = 0; kk < 2; ++kk) {
        int rk = nt * 16 + lr;
        bf16x8 kf = *reinterpret_cast<const bf16x8*>(&Kl[cur][rk * 64 + (((kk * 4 + lg) ^ (rk & 7)) << 3)]);
        z = mfma16(qa[kk], kf, z);
      }
      sv[nt] = z * 0.125f;
    }
    __builtin_amdgcn_s_setprio(0);
    // ---- online softmax ----
#pragma unroll
    for (int rg = 0; rg < 4; ++rg) {
      float tm = fmaxf(fmaxf(sv[0][rg], sv[1][rg]), fmaxf(sv[2][rg], sv[3][rg]));
#pragma unroll
      for (int mm = 1; mm < 16; mm <<= 1) tm = fmaxf(tm, __shfl_xor(tm, mm));
      float mn = fmaxf(mrun[rg], tm);
      float al = __expf(mrun[rg] - mn);
      mrun[rg] = mn;
      lsum[rg] *= al;
#pragma unroll
      for (int nt = 0; nt < 4; ++nt) oacc[nt][rg] *= al;
    }
#pragma unroll
    for (int nt = 0; nt < 4; ++nt) {
#pragma unroll
      for (int rg = 0; rg < 4; ++rg) {
        float p = __expf(sv[nt][rg] - mrun[rg]);
        lsum[rg] += p;
        int prow = lg * 4 + rg;
        Pl[w * 1024 + prow * 64 + ((nt * 16 + lr) ^ ((prow & 7) << 3))] = f2bf(p);
      }
    }
    // ---- PV ----
    __builtin_amdgcn_s_setprio(1);
#pragma unroll
    for (int kk = 0; kk < 2; ++kk) {
      bf16x8 pf = *reinterpret_cast<const bf16x8*>(
          Pl + w * 1024 + lr * 64 + (((kk * 4 + lg) ^ (lr & 7)) << 3));
#pragma unroll
      for (int nt = 0; nt < 4; ++nt) {
        int rv = nt * 16 + lr;
        bf16x8 vf = *reinterpret_cast<const bf16x8*>(
            reinterpret_cast<const u16*>(Vtl[cur]) + rv * 64 + (((kk * 4 + lg) ^ (rv & 7)) << 3));
        oacc[nt] = mfma16(pf, vf, oacc[nt]);
      }
    }
    __builtin_amdgcn_s_setprio(0);
  }
  // ---- epilogue: normalize, apply gate, store ----
#pragma unroll
  for (int rg = 0; rg < 4; ++rg) {
#pragma unroll
    for (int mm = 1; mm < 16; mm <<= 1) lsum[rg] += __shfl_xor(lsum[rg], mm);
    float gv = gvec[q0 + lg * 4 + rg];
    float inv = gv / lsum[rg];
#pragma unroll
    for (int nt = 0; nt < 4; ++nt)
      Og[(size_t)(q0 + lg * 4 + rg) * 1024 + nt * 16 + lr] = f2bf(oacc[nt][rg] * inv);
  }
}

// ---------- output projection: out += o_e(gated) @ oW_e^T ----------
__global__ __launch_bounds__(256) void oproj_kernel(
    const u16* __restrict__ o_all, const u16* __restrict__ wb_o,
    float* __restrict__ out) {
  __shared__ u16 lds[16384];
  int mblk = blockIdx.x, nblk = blockIdx.y, ez = blockIdx.z;
  const u16* A = o_all + ((size_t)ez * 2048 + (size_t)mblk * 128) * 1024;
  const u16* B = wb_o + ((size_t)ez * 1024 + (size_t)nblk * 128) * 1024;
  f32x4 acc[4][4];
#pragma unroll
  for (int i = 0; i < 4; ++i)
#pragma unroll
    for (int j = 0; j < 4; ++j) { f32x4 z = {0.f, 0.f, 0.f, 0.f}; acc[i][j] = z; }
  gemm_mainloop(A, 1024, B, 1024, 1024, lds, lds + 8192, acc);

  const int t = threadIdx.x, w = t >> 6, lane = t & 63;
  const int wm = (w >> 1) * 64, wn = (w & 1) * 64;
  const int lr = lane & 15, lg = lane >> 4;
  float* Ob = out + (size_t)mblk * 128 * 1024 + (size_t)nblk * 128;
#pragma unroll
  for (int mi = 0; mi < 4; ++mi)
#pragma unroll
    for (int rg = 0; rg < 4; ++rg) {
      int lrow = wm + mi * 16 + lg * 4 + rg;
#pragma unroll
      for (int ni = 0; ni < 4; ++ni) {
        int lcol = wn + ni * 16 + lr;
        atomicAdd(Ob + (size_t)lrow * 1024 + lcol, acc[mi][ni][rg]);
      }
    }
}

// ---------- host launcher ----------
extern "C" void kernel_launch(void* const* d_in, const int* in_sizes, int n_in,
                              void* d_out, int out_size, void* d_ws, size_t ws_size,
                              hipStream_t stream) {
  const float* x    = (const float*)d_in[0];
  const float* rW1  = (const float*)d_in[1];
  const float* rb1  = (const float*)d_in[2];
  const float* ln_g = (const float*)d_in[3];
  const float* ln_b = (const float*)d_in[4];
  const float* rW2  = (const float*)d_in[5];
  const float* rb2  = (const float*)d_in[6];
  const float* qW   = (const float*)d_in[7];
  const float* qb   = (const float*)d_in[8];
  const float* kW   = (const float*)d_in[9];
  const float* kb   = (const float*)d_in[10];
  const float* vW   = (const float*)d_in[11];
  const float* vb   = (const float*)d_in[12];
  const float* oW   = (const float*)d_in[13];
  const float* ob   = (const float*)d_in[14];
  float* out = (float*)d_out;

  const size_t fixed = 4194304ull /*xb*/ + 4194304ull /*hbuf*/ + 65536ull /*gates*/;
  const size_t perE = 6291456ull /*wb_qkv*/ + 2097152ull /*wb_o*/ +
                      12582912ull /*qkv*/ + 4194304ull /*o_all*/;
  int G = 0;
  const int cand[4] = {8, 4, 2, 1};
  for (int ci = 0; ci < 4; ++ci)
    if ((size_t)cand[ci] * perE + fixed <= ws_size) { G = cand[ci]; break; }
  if (G == 0) return;

  char* p = (char*)d_ws;
  u16* wb_qkv = (u16*)p; p += (size_t)G * 6291456ull;
  u16* wb_o   = (u16*)p; p += (size_t)G * 2097152ull;
  u16* qkvbuf = (u16*)p; p += (size_t)G * 12582912ull;
  u16* o_all  = (u16*)p; p += (size_t)G * 4194304ull;
  u16* xb     = (u16*)p; p += 4194304ull;
  float* hbuf = (float*)p; p += 4194304ull;
  float* gates = (float*)p;

  cvt_x_kernel<<<dim3(2048), dim3(256), 0, stream>>>(x, xb);
  router_gemm1<<<dim3(32, 8), dim3(256), 0, stream>>>(x, rW1, rb1, hbuf);
  router_finish<<<dim3(2048), dim3(64), 0, stream>>>(hbuf, ln_g, ln_b, rW2, rb2, gates);
  init_out_kernel<<<dim3(1024), dim3(256), 0, stream>>>(gates, ob, out);

  for (int e0 = 0; e0 < 8; e0 += G) {
    cvt_w_kernel<<<dim3(2048), dim3(256), 0, stream>>>(qW, kW, vW, oW, wb_qkv, wb_o, e0, G);
    qkv_gemm_kernel<<<dim3(G * 384), dim3(256), 0, stream>>>(xb, wb_qkv, qb, kb, vb, qkvbuf, e0, G);
    attn_kernel<<<dim3(G * 512), dim3(256), 0, stream>>>(qkvbuf, gates, o_all, e0, G);
    oproj_kernel<<<dim3(16, 8, G), dim3(256), 0, stream>>>(o_all, wb_o, out);
  }
}

// Round 3
// 654.955 us; speedup vs baseline: 1.1289x; 1.1289x over previous
//
#include <hip/hip_runtime.h>
#include <hip/hip_bf16.h>

typedef unsigned short u16;
typedef unsigned int u32;
typedef __bf16 bf16x8 __attribute__((ext_vector_type(8)));
typedef float f32x4 __attribute__((ext_vector_type(4)));

// ---------- helpers ----------
__device__ __forceinline__ u16 f2bf(float f) {
  union { float f; unsigned u; } v; v.f = f;
  unsigned r = v.u + 0x7fffu + ((v.u >> 16) & 1u);   // RNE
  return (u16)(r >> 16);
}

__device__ __forceinline__ f32x4 mfma16(bf16x8 a, bf16x8 b, f32x4 c) {
  return __builtin_amdgcn_mfma_f32_16x16x32_bf16(a, b, c, 0, 0, 0);
}

// async global->LDS, 16B/lane; LDS dest = wave-uniform base + lane*16
__device__ __forceinline__ void gl_lds16(const u16* g, u16* l) {
  __builtin_amdgcn_global_load_lds(
      (const __attribute__((address_space(1))) u32*)g,
      (__attribute__((address_space(3))) u32*)l, 16, 0, 0);
}

// ---------- bf16 conversion ----------
__global__ __launch_bounds__(256) void cvt_x_kernel(const float* __restrict__ x, u16* __restrict__ xb) {
  size_t i = (size_t)blockIdx.x * 256 + threadIdx.x;     // 524288 float4's
  float4 v = reinterpret_cast<const float4*>(x)[i];
  unsigned long long pk = (unsigned long long)f2bf(v.x) |
                          ((unsigned long long)f2bf(v.y) << 16) |
                          ((unsigned long long)f2bf(v.z) << 32) |
                          ((unsigned long long)f2bf(v.w) << 48);
  *reinterpret_cast<unsigned long long*>(xb + i * 4) = pk;
}

// all 8 experts: wb_qkv [8][3][1024][1024], wb_o [8][1024][1024]
__global__ __launch_bounds__(256) void cvt_w_kernel(
    const float* __restrict__ qW, const float* __restrict__ kW,
    const float* __restrict__ vW, const float* __restrict__ oW,
    u16* __restrict__ wb_qkv, u16* __restrict__ wb_o) {
  const size_t nqkv4 = (size_t)8 * 3 * 262144;
  const size_t total = nqkv4 + (size_t)8 * 262144;
  for (size_t i = (size_t)blockIdx.x * 256 + threadIdx.x; i < total;
       i += (size_t)gridDim.x * 256) {
    const float* src; u16* dst;
    if (i < nqkv4) {
      size_t elem = i * 4;
      size_t blk = elem >> 20;              // e*3 + type
      size_t el = blk / 3, ty = blk % 3;
      const float* W = (ty == 0 ? qW : (ty == 1 ? kW : vW));
      src = W + el * 1048576 + (elem & 1048575);
      dst = wb_qkv + elem;
    } else {
      size_t elem = (i - nqkv4) * 4;
      size_t el = elem >> 20;
      src = oW + el * 1048576 + (elem & 1048575);
      dst = wb_o + elem;
    }
    float4 v = *reinterpret_cast<const float4*>(src);
    unsigned long long pk = (unsigned long long)f2bf(v.x) |
                            ((unsigned long long)f2bf(v.y) << 16) |
                            ((unsigned long long)f2bf(v.z) << 32) |
                            ((unsigned long long)f2bf(v.w) << 48);
    *reinterpret_cast<unsigned long long*>(dst) = pk;
  }
}

// ---------- zero the list buffers (ws is poisoned before every call) ----------
__global__ __launch_bounds__(256) void zero_lists(u32* __restrict__ lists) {
  int i = blockIdx.x * 256 + threadIdx.x;
  if (i < 32784) lists[i] = 0;      // tok 16384 + gate 16384 + cnt 16
}

// ---------- router (fp32 for exact top-2 selection) ----------
__global__ __launch_bounds__(256) void router_gemm1(
    const float* __restrict__ x, const float* __restrict__ rW1,
    const float* __restrict__ rb1, float* __restrict__ hbuf) {
  __shared__ float aT[16][72];
  __shared__ float bT[16][72];
  int t = threadIdx.x;
  int tx = t & 15, ty = t >> 4;
  int m0 = blockIdx.x * 64, n0 = blockIdx.y * 64;
  float acc[4][4];
#pragma unroll
  for (int i = 0; i < 4; ++i)
#pragma unroll
    for (int j = 0; j < 4; ++j) acc[i][j] = 0.f;
  const float* Ab = x + (size_t)m0 * 1024;
  const float* Bb = rW1 + (size_t)n0 * 1024;
  int r = t >> 2, c4 = (t & 3) * 4;
  for (int k0 = 0; k0 < 1024; k0 += 16) {
    float4 av = *reinterpret_cast<const float4*>(Ab + (size_t)r * 1024 + k0 + c4);
    float4 bv = *reinterpret_cast<const float4*>(Bb + (size_t)r * 1024 + k0 + c4);
    aT[c4 + 0][r] = av.x; aT[c4 + 1][r] = av.y; aT[c4 + 2][r] = av.z; aT[c4 + 3][r] = av.w;
    bT[c4 + 0][r] = bv.x; bT[c4 + 1][r] = bv.y; bT[c4 + 2][r] = bv.z; bT[c4 + 3][r] = bv.w;
    __syncthreads();
#pragma unroll
    for (int kk = 0; kk < 16; ++kk) {
      float4 a = *reinterpret_cast<const float4*>(&aT[kk][ty * 4]);
      float4 b = *reinterpret_cast<const float4*>(&bT[kk][tx * 4]);
      float aa[4] = {a.x, a.y, a.z, a.w};
      float bb[4] = {b.x, b.y, b.z, b.w};
#pragma unroll
      for (int i = 0; i < 4; ++i)
#pragma unroll
        for (int j = 0; j < 4; ++j) acc[i][j] += aa[i] * bb[j];
    }
    __syncthreads();
  }
#pragma unroll
  for (int i = 0; i < 4; ++i) {
    int row = m0 + ty * 4 + i;
#pragma unroll
    for (int j = 0; j < 4; ++j) {
      int col = n0 + tx * 4 + j;
      hbuf[(size_t)row * 512 + col] = acc[i][j] + rb1[col];
    }
  }
}

__global__ __launch_bounds__(64) void router_finish(
    const float* __restrict__ hbuf, const float* __restrict__ ln_g,
    const float* __restrict__ ln_b, const float* __restrict__ rW2,
    const float* __restrict__ rb2, float* __restrict__ gates,
    u32* __restrict__ tok_list, float* __restrict__ gate_list, u32* __restrict__ cnt) {
  int tok = blockIdx.x, lane = threadIdx.x;
  const float* hr = hbuf + (size_t)tok * 512;
  float4 v0 = *reinterpret_cast<const float4*>(hr + lane * 8);
  float4 v1 = *reinterpret_cast<const float4*>(hr + lane * 8 + 4);
  float hv[8] = {v0.x, v0.y, v0.z, v0.w, v1.x, v1.y, v1.z, v1.w};
  float s = 0.f;
#pragma unroll
  for (int j = 0; j < 8; ++j) s += hv[j];
#pragma unroll
  for (int m = 1; m < 64; m <<= 1) s += __shfl_xor(s, m);
  float mu = s * (1.0f / 512.0f);
  float s2 = 0.f;
#pragma unroll
  for (int j = 0; j < 8; ++j) { float d = hv[j] - mu; s2 += d * d; }
#pragma unroll
  for (int m = 1; m < 64; m <<= 1) s2 += __shfl_xor(s2, m);
  float rstd = 1.0f / sqrtf(s2 * (1.0f / 512.0f) + 1e-5f);
#pragma unroll
  for (int j = 0; j < 8; ++j) {
    float tv = (hv[j] - mu) * rstd * ln_g[lane * 8 + j] + ln_b[lane * 8 + j];
    hv[j] = fmaxf(tv, 0.0f);
  }
  float logit[8];
#pragma unroll
  for (int n = 0; n < 8; ++n) {
    const float* wr = rW2 + (size_t)n * 512 + lane * 8;
    float p = 0.f;
#pragma unroll
    for (int j = 0; j < 8; ++j) p += hv[j] * wr[j];
#pragma unroll
    for (int m = 1; m < 64; m <<= 1) p += __shfl_xor(p, m);
    logit[n] = p + rb2[n];
  }
  int i1 = 0; float l1 = logit[0];
#pragma unroll
  for (int n = 1; n < 8; ++n) if (logit[n] > l1) { l1 = logit[n]; i1 = n; }
  int i2 = -1; float l2 = -3.4e38f;
#pragma unroll
  for (int n = 0; n < 8; ++n) if (n != i1 && logit[n] > l2) { l2 = logit[n]; i2 = n; }
  float e2 = __expf(l2 - l1);
  float g1 = 1.0f / (1.0f + e2);
  float g2 = e2 * g1;
  if (lane < 8) gates[(size_t)lane * 2048 + tok] = (lane == i1) ? g1 : ((lane == i2) ? g2 : 0.0f);
  if (lane == 0) {
    int b = tok >> 10, sq = tok & 1023;
    int p1 = i1 * 2 + b;
    u32 pos1 = atomicAdd(&cnt[p1], 1u);
    tok_list[p1 * 1024 + pos1] = (u32)sq;
    gate_list[p1 * 1024 + pos1] = g1;
    int p2 = i2 * 2 + b;
    u32 pos2 = atomicAdd(&cnt[p2], 1u);
    tok_list[p2 * 1024 + pos2] = (u32)sq;
    gate_list[p2 * 1024 + pos2] = g2;
  }
}

// out[t][n] = sum_e gates[e][t] * ob[e][n]   (bias; zero-inits out)
__global__ __launch_bounds__(256) void init_out_kernel(
    const float* __restrict__ gates, const float* __restrict__ ob, float* __restrict__ out) {
  for (size_t i = (size_t)blockIdx.x * 256 + threadIdx.x; i < 524288;
       i += (size_t)gridDim.x * 256) {
    int tok = (int)(i >> 8);
    int c4 = (int)(i & 255) * 4;
    float4 acc = {0.f, 0.f, 0.f, 0.f};
#pragma unroll
    for (int e = 0; e < 8; ++e) {
      float g = gates[(size_t)e * 2048 + tok];
      float4 bv = *reinterpret_cast<const float4*>(ob + (size_t)e * 1024 + c4);
      acc.x += g * bv.x; acc.y += g * bv.y; acc.z += g * bv.z; acc.w += g * bv.w;
    }
    *reinterpret_cast<float4*>(out + (size_t)tok * 1024 + c4) = acc;
  }
}

// ---------- 128x128 bf16 MFMA mainloop (pointer form; m97 gload_lds + swizzle) ----------
__device__ __forceinline__ void gemm_mainloop_p(
    const u16* aS0, const u16* aS1, const u16* aS2, const u16* aS3,
    const u16* bS0, const u16* bS1, const u16* bS2, const u16* bS3,
    int K, u16* aL, u16* bL, f32x4 acc[4][4]) {
  const int t = threadIdx.x;
  const int w = t >> 6, lane = t & 63;
  const int wm = (w >> 1) * 64, wn = (w & 1) * 64;
  const int lr = lane & 15, lg = lane >> 4;
  for (int k0 = 0; k0 < K; k0 += 64) {
    gl_lds16(aS0 + k0, aL + (32 * w + 0) * 64);
    gl_lds16(aS1 + k0, aL + (32 * w + 8) * 64);
    gl_lds16(aS2 + k0, aL + (32 * w + 16) * 64);
    gl_lds16(aS3 + k0, aL + (32 * w + 24) * 64);
    gl_lds16(bS0 + k0, bL + (32 * w + 0) * 64);
    gl_lds16(bS1 + k0, bL + (32 * w + 8) * 64);
    gl_lds16(bS2 + k0, bL + (32 * w + 16) * 64);
    gl_lds16(bS3 + k0, bL + (32 * w + 24) * 64);
    __syncthreads();
#pragma unroll
    for (int kk = 0; kk < 2; ++kk) {
      bf16x8 af[4], bfr[4];
#pragma unroll
      for (int i = 0; i < 4; ++i) {
        int ra = wm + i * 16 + lr;
        af[i] = *reinterpret_cast<const bf16x8*>(aL + ra * 64 + (((kk * 4 + lg) ^ (ra & 7)) << 3));
        int rb = wn + i * 16 + lr;
        bfr[i] = *reinterpret_cast<const bf16x8*>(bL + rb * 64 + (((kk * 4 + lg) ^ (rb & 7)) << 3));
      }
#pragma unroll
      for (int mi = 0; mi < 4; ++mi)
#pragma unroll
        for (int ni = 0; ni < 4; ++ni)
          acc[mi][ni] = mfma16(af[mi], bfr[ni], acc[mi][ni]);
    }
    __syncthreads();
  }
}

// ---------- K/V dense GEMM: kvbuf[e][ty][2048][1024] = xb @ W^T + bias ----------
__global__ __launch_bounds__(256) void kv_gemm_kernel(
    const u16* __restrict__ xb, const u16* __restrict__ wb_qkv,
    const float* __restrict__ kb, const float* __restrict__ vb,
    u16* __restrict__ kvbuf) {
  __shared__ u16 lds[16384];
  int orig = blockIdx.x;                         // 2048, %8==0
  int wgid = (orig & 7) * 256 + (orig >> 3);     // XCD-bijective swizzle
  int nblk = wgid & 7, mblk = (wgid >> 3) & 15;
  int ty = (wgid >> 7) & 1, e = wgid >> 8;
  const int t = threadIdx.x, w = t >> 6, lane = t & 63;
  const int rloc = lane >> 3, cloc = lane & 7;
  const int sc8 = (cloc ^ rloc) * 8;
  const u16* A = xb + (size_t)mblk * 128 * 1024;
  const u16* B = wb_qkv + (size_t)(e * 3 + 1 + ty) * 1048576 + (size_t)nblk * 128 * 1024;
  f32x4 acc[4][4];
#pragma unroll
  for (int i = 0; i < 4; ++i)
#pragma unroll
    for (int j = 0; j < 4; ++j) { f32x4 z = {0.f, 0.f, 0.f, 0.f}; acc[i][j] = z; }
  gemm_mainloop_p(
      A + (size_t)(32 * w + 0 + rloc) * 1024 + sc8, A + (size_t)(32 * w + 8 + rloc) * 1024 + sc8,
      A + (size_t)(32 * w + 16 + rloc) * 1024 + sc8, A + (size_t)(32 * w + 24 + rloc) * 1024 + sc8,
      B + (size_t)(32 * w + 0 + rloc) * 1024 + sc8, B + (size_t)(32 * w + 8 + rloc) * 1024 + sc8,
      B + (size_t)(32 * w + 16 + rloc) * 1024 + sc8, B + (size_t)(32 * w + 24 + rloc) * 1024 + sc8,
      1024, lds, lds + 8192, acc);
  const int wm = (w >> 1) * 64, wn = (w & 1) * 64;
  const int lr = lane & 15, lg = lane >> 4;
  const float* bias = (ty ? vb : kb) + (size_t)e * 1024 + nblk * 128;
  u16* Cb = kvbuf + ((size_t)(e * 2 + ty) * 2048 + (size_t)mblk * 128) * 1024 + nblk * 128;
#pragma unroll
  for (int ni = 0; ni < 4; ++ni) {
    int lcol = wn + ni * 16 + lr;
    float bv = bias[lcol];
#pragma unroll
    for (int mi = 0; mi < 4; ++mi)
#pragma unroll
      for (int rg = 0; rg < 4; ++rg) {
        int lrow = wm + mi * 16 + lg * 4 + rg;
        Cb[(size_t)lrow * 1024 + lcol] = f2bf(acc[mi][ni][rg] + bv);
      }
  }
}

// ---------- Q gathered GEMM: qc[p][pos][1024] = xb[tok rows] @ qW_e^T + qb ----------
__global__ __launch_bounds__(256) void q_gemm_kernel(
    const u16* __restrict__ xb, const u16* __restrict__ wb_qkv,
    const float* __restrict__ qb, const u32* __restrict__ tok_list,
    const u32* __restrict__ cnt, u16* __restrict__ qc) {
  __shared__ u16 lds[16384];
  int nblk = blockIdx.x, mt = blockIdx.y, p = blockIdx.z;
  int c = (int)cnt[p];
  if (mt * 128 >= c) return;
  int e = p >> 1, b = p & 1;
  const int t = threadIdx.x, w = t >> 6, lane = t & 63;
  const int rloc = lane >> 3, cloc = lane & 7;
  const int sc8 = (cloc ^ rloc) * 8;
  const u32* tl = tok_list + p * 1024 + mt * 128 + 32 * w + rloc;
  int t0 = (int)(tl[0] & 1023), t1 = (int)(tl[8] & 1023);
  int t2 = (int)(tl[16] & 1023), t3 = (int)(tl[24] & 1023);
  const u16* Ab = xb + (size_t)b * 1024 * 1024 + sc8;
  const u16* B = wb_qkv + (size_t)(e * 3) * 1048576 + (size_t)nblk * 128 * 1024;
  f32x4 acc[4][4];
#pragma unroll
  for (int i = 0; i < 4; ++i)
#pragma unroll
    for (int j = 0; j < 4; ++j) { f32x4 z = {0.f, 0.f, 0.f, 0.f}; acc[i][j] = z; }
  gemm_mainloop_p(
      Ab + (size_t)t0 * 1024, Ab + (size_t)t1 * 1024, Ab + (size_t)t2 * 1024, Ab + (size_t)t3 * 1024,
      B + (size_t)(32 * w + 0 + rloc) * 1024 + sc8, B + (size_t)(32 * w + 8 + rloc) * 1024 + sc8,
      B + (size_t)(32 * w + 16 + rloc) * 1024 + sc8, B + (size_t)(32 * w + 24 + rloc) * 1024 + sc8,
      1024, lds, lds + 8192, acc);
  const int wm = (w >> 1) * 64, wn = (w & 1) * 64;
  const int lr = lane & 15, lg = lane >> 4;
  const float* bias = qb + (size_t)e * 1024 + nblk * 128;
  u16* Cb = qc + ((size_t)p * 1024 + (size_t)mt * 128) * 1024 + nblk * 128;
#pragma unroll
  for (int ni = 0; ni < 4; ++ni) {
    int lcol = wn + ni * 16 + lr;
    float bv = bias[lcol];
#pragma unroll
    for (int mi = 0; mi < 4; ++mi)
#pragma unroll
      for (int rg = 0; rg < 4; ++rg) {
        int lrow = wm + mi * 16 + lg * 4 + rg;
        Cb[(size_t)lrow * 1024 + lcol] = f2bf(acc[mi][ni][rg] + bv);
      }
  }
}

// ---------- sparse flash attention: 64 compact Q rows per block ----------
__global__ __launch_bounds__(256) void attn_kernel(
    const u16* __restrict__ qc, const u16* __restrict__ kvbuf,
    const u32* __restrict__ cnt, u16* __restrict__ oc) {
  __shared__ u16 Kl[4096];       // [tok 64][dh 64], XOR-swizzled via source
  __shared__ u32 Vtl[2048];      // [dh 64][tokpair 32], chunk-swizzled
  __shared__ u16 Pl[4096];       // per-wave 1024
  int h = blockIdx.x;
  int p = blockIdx.y >> 3, lt = blockIdx.y & 7;
  int c = (int)cnt[p];
  if (lt * 64 >= c) return;
  int e = p >> 1, b = p & 1;
  const u16* Qb = qc + ((size_t)p * 1024 + (size_t)lt * 64) * 1024 + h * 64;
  const u16* Kg = kvbuf + ((size_t)(e * 2 + 0) * 2048 + (size_t)b * 1024) * 1024 + h * 64;
  const u16* Vg = kvbuf + ((size_t)(e * 2 + 1) * 2048 + (size_t)b * 1024) * 1024 + h * 64;
  u16* Og = oc + ((size_t)p * 1024 + (size_t)lt * 64) * 1024 + h * 64;
  const int t = threadIdx.x, w = t >> 6, lane = t & 63;
  const int lr = lane & 15, lg = lane >> 4;
  const int krow_l = lane >> 3, kc = lane & 7;
  const int s2 = t >> 3, sc3 = t & 7;

  bf16x8 qa0 = *reinterpret_cast<const bf16x8*>(Qb + (size_t)(w * 16 + lr) * 1024 + lg * 8);
  bf16x8 qa1 = *reinterpret_cast<const bf16x8*>(Qb + (size_t)(w * 16 + lr) * 1024 + 32 + lg * 8);

  f32x4 oacc[4];
  float mrun[4], lsum[4];
#pragma unroll
  for (int i = 0; i < 4; ++i) {
    f32x4 z = {0.f, 0.f, 0.f, 0.f}; oacc[i] = z; mrun[i] = -3.4e38f; lsum[i] = 0.f;
  }

  for (int it = 0; it < 16; ++it) {
    int kv0 = it * 64;
    // stage K via gload_lds (wave w -> rows 16w..16w+15)
#pragma unroll
    for (int r = 0; r < 2; ++r) {
      int row = 16 * w + 8 * r + krow_l;
      gl_lds16(Kg + (size_t)(kv0 + row) * 1024 + (kc ^ (row & 7)) * 8,
               Kl + (16 * w + 8 * r) * 64);
    }
    // V^T pair-packed staging (named regs; conflict-free rotated writes)
    {
      int4 v0r = *reinterpret_cast<const int4*>(Vg + (size_t)(kv0 + 2 * s2) * 1024 + sc3 * 8);
      int4 v1r = *reinterpret_cast<const int4*>(Vg + (size_t)(kv0 + 2 * s2 + 1) * 1024 + sc3 * 8);
      const u16* v0 = reinterpret_cast<const u16*>(&v0r);
      const u16* v1 = reinterpret_cast<const u16*>(&v1r);
#pragma unroll
      for (int j = 0; j < 8; ++j) {
        int jj = (j + sc3) & 7;
        int d = sc3 * 8 + jj;
        u32 val = (u32)v0[jj] | ((u32)v1[jj] << 16);
        Vtl[d * 32 + (((s2 >> 2) ^ (d & 7)) << 2) + (s2 & 3)] = val;
      }
    }
    __syncthreads();
    // QK^T
    f32x4 sv[4];
    __builtin_amdgcn_s_setprio(1);
#pragma unroll
    for (int nt = 0; nt < 4; ++nt) {
      f32x4 z = {0.f, 0.f, 0.f, 0.f};
#pragma unroll
      for (int kk = 0; kk < 2; ++kk) {
        int rk = nt * 16 + lr;
        bf16x8 kf = *reinterpret_cast<const bf16x8*>(Kl + rk * 64 + (((kk * 4 + lg) ^ (rk & 7)) << 3));
        z = mfma16(kk ? qa1 : qa0, kf, z);
      }
      sv[nt] = z * 0.125f;
    }
    __builtin_amdgcn_s_setprio(0);
    // online softmax
#pragma unroll
    for (int rg = 0; rg < 4; ++rg) {
      float tm = fmaxf(fmaxf(sv[0][rg], sv[1][rg]), fmaxf(sv[2][rg], sv[3][rg]));
#pragma unroll
      for (int mm = 1; mm < 16; mm <<= 1) tm = fmaxf(tm, __shfl_xor(tm, mm));
      float mn = fmaxf(mrun[rg], tm);
      float al = __expf(mrun[rg] - mn);
      mrun[rg] = mn;
      lsum[rg] *= al;
#pragma unroll
      for (int nt = 0; nt < 4; ++nt) oacc[nt][rg] *= al;
    }
#pragma unroll
    for (int nt = 0; nt < 4; ++nt) {
#pragma unroll
      for (int rg = 0; rg < 4; ++rg) {
        float pv = __expf(sv[nt][rg] - mrun[rg]);
        lsum[rg] += pv;
        int prow = lg * 4 + rg;
        Pl[w * 1024 + prow * 64 + ((nt * 16 + lr) ^ ((prow & 7) << 3))] = f2bf(pv);
      }
    }
    // PV
    __builtin_amdgcn_s_setprio(1);
#pragma unroll
    for (int kk = 0; kk < 2; ++kk) {
      bf16x8 pf = *reinterpret_cast<const bf16x8*>(
          Pl + w * 1024 + lr * 64 + (((kk * 4 + lg) ^ (lr & 7)) << 3));
#pragma unroll
      for (int nt = 0; nt < 4; ++nt) {
        int rv = nt * 16 + lr;
        bf16x8 vf = *reinterpret_cast<const bf16x8*>(
            reinterpret_cast<const u16*>(Vtl) + rv * 64 + (((kk * 4 + lg) ^ (rv & 7)) << 3));
        oacc[nt] = mfma16(pf, vf, oacc[nt]);
      }
    }
    __builtin_amdgcn_s_setprio(0);
    __syncthreads();
  }
#pragma unroll
  for (int rg = 0; rg < 4; ++rg) {
#pragma unroll
    for (int mm = 1; mm < 16; mm <<= 1) lsum[rg] += __shfl_xor(lsum[rg], mm);
    float inv = 1.0f / lsum[rg];
#pragma unroll
    for (int nt = 0; nt < 4; ++nt)
      Og[(size_t)(w * 16 + lg * 4 + rg) * 1024 + nt * 16 + lr] = f2bf(oacc[nt][rg] * inv);
  }
}

// ---------- gated output projection (compact rows, scatter) ----------
__global__ __launch_bounds__(256) void oproj_kernel(
    const u16* __restrict__ oc, const u16* __restrict__ wb_o,
    const u32* __restrict__ tok_list, const float* __restrict__ gate_list,
    const u32* __restrict__ cnt, float* __restrict__ out) {
  __shared__ u16 lds[16384];
  int nblk = blockIdx.x, mt = blockIdx.y, p = blockIdx.z;
  int c = (int)cnt[p];
  if (mt * 128 >= c) return;
  int e = p >> 1, b = p & 1;
  const int t = threadIdx.x, w = t >> 6, lane = t & 63;
  const int rloc = lane >> 3, cloc = lane & 7;
  const int sc8 = (cloc ^ rloc) * 8;
  const u16* A = oc + ((size_t)p * 1024 + (size_t)mt * 128) * 1024;
  const u16* B = wb_o + (size_t)e * 1048576 + (size_t)nblk * 128 * 1024;
  f32x4 acc[4][4];
#pragma unroll
  for (int i = 0; i < 4; ++i)
#pragma unroll
    for (int j = 0; j < 4; ++j) { f32x4 z = {0.f, 0.f, 0.f, 0.f}; acc[i][j] = z; }
  gemm_mainloop_p(
      A + (size_t)(32 * w + 0 + rloc) * 1024 + sc8, A + (size_t)(32 * w + 8 + rloc) * 1024 + sc8,
      A + (size_t)(32 * w + 16 + rloc) * 1024 + sc8, A + (size_t)(32 * w + 24 + rloc) * 1024 + sc8,
      B + (size_t)(32 * w + 0 + rloc) * 1024 + sc8, B + (size_t)(32 * w + 8 + rloc) * 1024 + sc8,
      B + (size_t)(32 * w + 16 + rloc) * 1024 + sc8, B + (size_t)(32 * w + 24 + rloc) * 1024 + sc8,
      1024, lds, lds + 8192, acc);
  const int wm = (w >> 1) * 64, wn = (w & 1) * 64;
  const int lr = lane & 15, lg = lane >> 4;
#pragma unroll
  for (int mi = 0; mi < 4; ++mi)
#pragma unroll
    for (int rg = 0; rg < 4; ++rg) {
      int pos = mt * 128 + wm + mi * 16 + lg * 4 + rg;
      float gv = gate_list[p * 1024 + pos];
      int sq = (int)(tok_list[p * 1024 + pos] & 1023);
      float* Ob = out + ((size_t)b * 1024 + sq) * 1024 + nblk * 128;
#pragma unroll
      for (int ni = 0; ni < 4; ++ni) {
        int lcol = wn + ni * 16 + lr;
        atomicAdd(Ob + lcol, gv * acc[mi][ni][rg]);
      }
    }
}

// ---------- host launcher ----------
extern "C" void kernel_launch(void* const* d_in, const int* in_sizes, int n_in,
                              void* d_out, int out_size, void* d_ws, size_t ws_size,
                              hipStream_t stream) {
  const float* x    = (const float*)d_in[0];
  const float* rW1  = (const float*)d_in[1];
  const float* rb1  = (const float*)d_in[2];
  const float* ln_g = (const float*)d_in[3];
  const float* ln_b = (const float*)d_in[4];
  const float* rW2  = (const float*)d_in[5];
  const float* rb2  = (const float*)d_in[6];
  const float* qW   = (const float*)d_in[7];
  const float* qb   = (const float*)d_in[8];
  const float* kW   = (const float*)d_in[9];
  const float* kb   = (const float*)d_in[10];
  const float* vW   = (const float*)d_in[11];
  const float* vb   = (const float*)d_in[12];
  const float* oW   = (const float*)d_in[13];
  const float* ob   = (const float*)d_in[14];
  float* out = (float*)d_out;

  // ws layout (205.7 MB total; hbuf aliased into qc)
  const size_t need = 50331648ull + 16777216ull + 67108864ull + 33554432ull +
                      33554432ull + 4194304ull + 65536ull + 131136ull;
  if (ws_size < need) return;
  char* pp = (char*)d_ws;
  u16* wb_qkv = (u16*)pp; pp += 50331648ull;   // [8][3][1024][1024]
  u16* wb_o   = (u16*)pp; pp += 16777216ull;   // [8][1024][1024]
  u16* kvbuf  = (u16*)pp; pp += 67108864ull;   // [8][2][2048][1024]
  u16* qc     = (u16*)pp; pp += 33554432ull;   // [16][1024][1024]
  u16* oc     = (u16*)pp; pp += 33554432ull;   // [16][1024][1024]
  u16* xb     = (u16*)pp; pp += 4194304ull;    // [2048][1024]
  float* gates = (float*)pp; pp += 65536ull;   // [8][2048]
  u32* lists  = (u32*)pp;                      // tok 16K + gate 16K + cnt 16
  u32* tok_list   = lists;
  float* gate_list = (float*)(lists + 16384);
  u32* cnt        = lists + 32768;
  float* hbuf = (float*)qc;                    // alias (used before qc written)

  cvt_x_kernel<<<dim3(2048), dim3(256), 0, stream>>>(x, xb);
  router_gemm1<<<dim3(32, 8), dim3(256), 0, stream>>>(x, rW1, rb1, hbuf);
  zero_lists<<<dim3(129), dim3(256), 0, stream>>>(lists);
  router_finish<<<dim3(2048), dim3(64), 0, stream>>>(hbuf, ln_g, ln_b, rW2, rb2,
                                                     gates, tok_list, gate_list, cnt);
  init_out_kernel<<<dim3(1024), dim3(256), 0, stream>>>(gates, ob, out);
  cvt_w_kernel<<<dim3(2048), dim3(256), 0, stream>>>(qW, kW, vW, oW, wb_qkv, wb_o);
  kv_gemm_kernel<<<dim3(2048), dim3(256), 0, stream>>>(xb, wb_qkv, kb, vb, kvbuf);
  q_gemm_kernel<<<dim3(8, 8, 16), dim3(256), 0, stream>>>(xb, wb_qkv, qb, tok_list, cnt, qc);
  attn_kernel<<<dim3(16, 128), dim3(256), 0, stream>>>(qc, kvbuf, cnt, oc);
  oproj_kernel<<<dim3(8, 8, 16), dim3(256), 0, stream>>>(oc, wb_o, tok_list, gate_list, cnt, out);
}

// Round 4
// 539.454 us; speedup vs baseline: 1.3706x; 1.2141x over previous
//
#include <hip/hip_runtime.h>
#include <hip/hip_bf16.h>

typedef unsigned short u16;
typedef unsigned int u32;
typedef __bf16 bf16x8 __attribute__((ext_vector_type(8)));
typedef float f32x4 __attribute__((ext_vector_type(4)));

// ---------- helpers ----------
__device__ __forceinline__ u16 f2bf(float f) {
  union { float f; unsigned u; } v; v.f = f;
  unsigned r = v.u + 0x7fffu + ((v.u >> 16) & 1u);   // RNE
  return (u16)(r >> 16);
}

__device__ __forceinline__ f32x4 mfma16(bf16x8 a, bf16x8 b, f32x4 c) {
  return __builtin_amdgcn_mfma_f32_16x16x32_bf16(a, b, c, 0, 0, 0);
}

// async global->LDS, 16B/lane; LDS dest = wave-uniform base + lane*16
__device__ __forceinline__ void gl_lds16(const u16* g, u16* l) {
  __builtin_amdgcn_global_load_lds(
      (const __attribute__((address_space(1))) u32*)g,
      (__attribute__((address_space(3))) u32*)l, 16, 0, 0);
}

// ---------- bf16 conversion ----------
__global__ __launch_bounds__(256) void cvt_x_kernel(const float* __restrict__ x, u16* __restrict__ xb) {
  size_t i = (size_t)blockIdx.x * 256 + threadIdx.x;     // 524288 float4's
  float4 v = reinterpret_cast<const float4*>(x)[i];
  unsigned long long pk = (unsigned long long)f2bf(v.x) |
                          ((unsigned long long)f2bf(v.y) << 16) |
                          ((unsigned long long)f2bf(v.z) << 32) |
                          ((unsigned long long)f2bf(v.w) << 48);
  *reinterpret_cast<unsigned long long*>(xb + i * 4) = pk;
}

// all 8 experts: wb_qkv [8][3][1024][1024], wb_o [8][1024][1024]
__global__ __launch_bounds__(256) void cvt_w_kernel(
    const float* __restrict__ qW, const float* __restrict__ kW,
    const float* __restrict__ vW, const float* __restrict__ oW,
    u16* __restrict__ wb_qkv, u16* __restrict__ wb_o) {
  const size_t nqkv4 = (size_t)8 * 3 * 262144;
  const size_t total = nqkv4 + (size_t)8 * 262144;
  for (size_t i = (size_t)blockIdx.x * 256 + threadIdx.x; i < total;
       i += (size_t)gridDim.x * 256) {
    const float* src; u16* dst;
    if (i < nqkv4) {
      size_t elem = i * 4;
      size_t blk = elem >> 20;              // e*3 + type
      size_t el = blk / 3, ty = blk % 3;
      const float* W = (ty == 0 ? qW : (ty == 1 ? kW : vW));
      src = W + el * 1048576 + (elem & 1048575);
      dst = wb_qkv + elem;
    } else {
      size_t elem = (i - nqkv4) * 4;
      size_t el = elem >> 20;
      src = oW + el * 1048576 + (elem & 1048575);
      dst = wb_o + elem;
    }
    float4 v = *reinterpret_cast<const float4*>(src);
    unsigned long long pk = (unsigned long long)f2bf(v.x) |
                            ((unsigned long long)f2bf(v.y) << 16) |
                            ((unsigned long long)f2bf(v.z) << 32) |
                            ((unsigned long long)f2bf(v.w) << 48);
    *reinterpret_cast<unsigned long long*>(dst) = pk;
  }
}

// ---------- zero the list buffers (ws poisoned before every call) ----------
__global__ __launch_bounds__(256) void zero_lists(u32* __restrict__ lists) {
  int i = blockIdx.x * 256 + threadIdx.x;
  if (i < 32784) lists[i] = 0;      // tok 16384 + gate 16384 + cnt 16
}

// ---------- router (fp32 for exact top-2 selection) ----------
__global__ __launch_bounds__(256) void router_gemm1(
    const float* __restrict__ x, const float* __restrict__ rW1,
    const float* __restrict__ rb1, float* __restrict__ hbuf) {
  __shared__ float aT[16][72];
  __shared__ float bT[16][72];
  int t = threadIdx.x;
  int tx = t & 15, ty = t >> 4;
  int m0 = blockIdx.x * 64, n0 = blockIdx.y * 64;
  float acc[4][4];
#pragma unroll
  for (int i = 0; i < 4; ++i)
#pragma unroll
    for (int j = 0; j < 4; ++j) acc[i][j] = 0.f;
  const float* Ab = x + (size_t)m0 * 1024;
  const float* Bb = rW1 + (size_t)n0 * 1024;
  int r = t >> 2, c4 = (t & 3) * 4;
  for (int k0 = 0; k0 < 1024; k0 += 16) {
    float4 av = *reinterpret_cast<const float4*>(Ab + (size_t)r * 1024 + k0 + c4);
    float4 bv = *reinterpret_cast<const float4*>(Bb + (size_t)r * 1024 + k0 + c4);
    aT[c4 + 0][r] = av.x; aT[c4 + 1][r] = av.y; aT[c4 + 2][r] = av.z; aT[c4 + 3][r] = av.w;
    bT[c4 + 0][r] = bv.x; bT[c4 + 1][r] = bv.y; bT[c4 + 2][r] = bv.z; bT[c4 + 3][r] = bv.w;
    __syncthreads();
#pragma unroll
    for (int kk = 0; kk < 16; ++kk) {
      float4 a = *reinterpret_cast<const float4*>(&aT[kk][ty * 4]);
      float4 b = *reinterpret_cast<const float4*>(&bT[kk][tx * 4]);
      float aa[4] = {a.x, a.y, a.z, a.w};
      float bb[4] = {b.x, b.y, b.z, b.w};
#pragma unroll
      for (int i = 0; i < 4; ++i)
#pragma unroll
        for (int j = 0; j < 4; ++j) acc[i][j] += aa[i] * bb[j];
    }
    __syncthreads();
  }
#pragma unroll
  for (int i = 0; i < 4; ++i) {
    int row = m0 + ty * 4 + i;
#pragma unroll
    for (int j = 0; j < 4; ++j) {
      int col = n0 + tx * 4 + j;
      hbuf[(size_t)row * 512 + col] = acc[i][j] + rb1[col];
    }
  }
}

__global__ __launch_bounds__(64) void router_finish(
    const float* __restrict__ hbuf, const float* __restrict__ ln_g,
    const float* __restrict__ ln_b, const float* __restrict__ rW2,
    const float* __restrict__ rb2,
    u32* __restrict__ tok_list, float* __restrict__ gate_list,
    u32* __restrict__ cnt, u32* __restrict__ inv) {
  int tok = blockIdx.x, lane = threadIdx.x;
  const float* hr = hbuf + (size_t)tok * 512;
  float4 v0 = *reinterpret_cast<const float4*>(hr + lane * 8);
  float4 v1 = *reinterpret_cast<const float4*>(hr + lane * 8 + 4);
  float hv[8] = {v0.x, v0.y, v0.z, v0.w, v1.x, v1.y, v1.z, v1.w};
  float s = 0.f;
#pragma unroll
  for (int j = 0; j < 8; ++j) s += hv[j];
#pragma unroll
  for (int m = 1; m < 64; m <<= 1) s += __shfl_xor(s, m);
  float mu = s * (1.0f / 512.0f);
  float s2 = 0.f;
#pragma unroll
  for (int j = 0; j < 8; ++j) { float d = hv[j] - mu; s2 += d * d; }
#pragma unroll
  for (int m = 1; m < 64; m <<= 1) s2 += __shfl_xor(s2, m);
  float rstd = 1.0f / sqrtf(s2 * (1.0f / 512.0f) + 1e-5f);
#pragma unroll
  for (int j = 0; j < 8; ++j) {
    float tv = (hv[j] - mu) * rstd * ln_g[lane * 8 + j] + ln_b[lane * 8 + j];
    hv[j] = fmaxf(tv, 0.0f);
  }
  float logit[8];
#pragma unroll
  for (int n = 0; n < 8; ++n) {
    const float* wr = rW2 + (size_t)n * 512 + lane * 8;
    float p = 0.f;
#pragma unroll
    for (int j = 0; j < 8; ++j) p += hv[j] * wr[j];
#pragma unroll
    for (int m = 1; m < 64; m <<= 1) p += __shfl_xor(p, m);
    logit[n] = p + rb2[n];
  }
  int i1 = 0; float l1 = logit[0];
#pragma unroll
  for (int n = 1; n < 8; ++n) if (logit[n] > l1) { l1 = logit[n]; i1 = n; }
  int i2 = -1; float l2 = -3.4e38f;
#pragma unroll
  for (int n = 0; n < 8; ++n) if (n != i1 && logit[n] > l2) { l2 = logit[n]; i2 = n; }
  float e2 = __expf(l2 - l1);
  float g1 = 1.0f / (1.0f + e2);
  float g2 = e2 * g1;
  if (lane == 0) {
    int b = tok >> 10, sq = tok & 1023;
    int p1 = i1 * 2 + b;
    u32 pos1 = atomicAdd(&cnt[p1], 1u);
    tok_list[p1 * 1024 + pos1] = (u32)sq;
    gate_list[p1 * 1024 + pos1] = g1;
    inv[tok * 2 + 0] = ((u32)p1 << 10) | pos1;
    int p2 = i2 * 2 + b;
    u32 pos2 = atomicAdd(&cnt[p2], 1u);
    tok_list[p2 * 1024 + pos2] = (u32)sq;
    gate_list[p2 * 1024 + pos2] = g2;
    inv[tok * 2 + 1] = ((u32)p2 << 10) | pos2;
  }
}

// ---------- 2-phase double-buffered 128x128 bf16 MFMA mainloop ----------
__device__ __forceinline__ void stage8(
    const u16* aS0, const u16* aS1, const u16* aS2, const u16* aS3,
    const u16* bS0, const u16* bS1, const u16* bS2, const u16* bS3,
    int k0, u16* aL, u16* bL, int w) {
  gl_lds16(aS0 + k0, aL + (32 * w + 0) * 64);
  gl_lds16(aS1 + k0, aL + (32 * w + 8) * 64);
  gl_lds16(aS2 + k0, aL + (32 * w + 16) * 64);
  gl_lds16(aS3 + k0, aL + (32 * w + 24) * 64);
  gl_lds16(bS0 + k0, bL + (32 * w + 0) * 64);
  gl_lds16(bS1 + k0, bL + (32 * w + 8) * 64);
  gl_lds16(bS2 + k0, bL + (32 * w + 16) * 64);
  gl_lds16(bS3 + k0, bL + (32 * w + 24) * 64);
}

__device__ __forceinline__ void gemm_mainloop_p(
    const u16* aS0, const u16* aS1, const u16* aS2, const u16* aS3,
    const u16* bS0, const u16* bS1, const u16* bS2, const u16* bS3,
    int K, u16* aL0, u16* bL0, u16* aL1, u16* bL1, f32x4 acc[4][4]) {
  const int t = threadIdx.x;
  const int w = t >> 6, lane = t & 63;
  const int wm = (w >> 1) * 64, wn = (w & 1) * 64;
  const int lr = lane & 15, lg = lane >> 4;
  const int T = K >> 6;
  stage8(aS0, aS1, aS2, aS3, bS0, bS1, bS2, bS3, 0, aL0, bL0, w);
  __syncthreads();
  for (int tt = 0; tt < T; ++tt) {
    u16* aC = (tt & 1) ? aL1 : aL0;
    u16* bC = (tt & 1) ? bL1 : bL0;
    if (tt + 1 < T) {
      u16* aN = (tt & 1) ? aL0 : aL1;
      u16* bN = (tt & 1) ? bL0 : bL1;
      stage8(aS0, aS1, aS2, aS3, bS0, bS1, bS2, bS3, (tt + 1) << 6, aN, bN, w);
    }
    __builtin_amdgcn_s_setprio(1);
#pragma unroll
    for (int kk = 0; kk < 2; ++kk) {
      bf16x8 af[4], bfr[4];
#pragma unroll
      for (int i = 0; i < 4; ++i) {
        int ra = wm + i * 16 + lr;
        af[i] = *reinterpret_cast<const bf16x8*>(aC + ra * 64 + (((kk * 4 + lg) ^ (ra & 7)) << 3));
        int rb = wn + i * 16 + lr;
        bfr[i] = *reinterpret_cast<const bf16x8*>(bC + rb * 64 + (((kk * 4 + lg) ^ (rb & 7)) << 3));
      }
#pragma unroll
      for (int mi = 0; mi < 4; ++mi)
#pragma unroll
        for (int ni = 0; ni < 4; ++ni)
          acc[mi][ni] = mfma16(af[mi], bfr[ni], acc[mi][ni]);
    }
    __builtin_amdgcn_s_setprio(0);
    __syncthreads();   // drains vmcnt(0): next tile resident; all reads of aC done
  }
}

// ---------- K/V dense GEMM: kvbuf[e][ty][2048][1024] = xb @ W^T + bias ----------
__global__ __launch_bounds__(256) void kv_gemm_kernel(
    const u16* __restrict__ xb, const u16* __restrict__ wb_qkv,
    const float* __restrict__ kb, const float* __restrict__ vb,
    u16* __restrict__ kvbuf) {
  __shared__ u16 lds[32768];
  int orig = blockIdx.x;                         // 2048, %8==0
  int wgid = (orig & 7) * 256 + (orig >> 3);     // XCD-bijective swizzle
  int nblk = wgid & 7, mblk = (wgid >> 3) & 15;
  int ty = (wgid >> 7) & 1, e = wgid >> 8;
  const int t = threadIdx.x, w = t >> 6, lane = t & 63;
  const int rloc = lane >> 3, cloc = lane & 7;
  const int sc8 = (cloc ^ rloc) * 8;
  const u16* A = xb + (size_t)mblk * 128 * 1024;
  const u16* B = wb_qkv + (size_t)(e * 3 + 1 + ty) * 1048576 + (size_t)nblk * 128 * 1024;
  f32x4 acc[4][4];
#pragma unroll
  for (int i = 0; i < 4; ++i)
#pragma unroll
    for (int j = 0; j < 4; ++j) { f32x4 z = {0.f, 0.f, 0.f, 0.f}; acc[i][j] = z; }
  gemm_mainloop_p(
      A + (size_t)(32 * w + 0 + rloc) * 1024 + sc8, A + (size_t)(32 * w + 8 + rloc) * 1024 + sc8,
      A + (size_t)(32 * w + 16 + rloc) * 1024 + sc8, A + (size_t)(32 * w + 24 + rloc) * 1024 + sc8,
      B + (size_t)(32 * w + 0 + rloc) * 1024 + sc8, B + (size_t)(32 * w + 8 + rloc) * 1024 + sc8,
      B + (size_t)(32 * w + 16 + rloc) * 1024 + sc8, B + (size_t)(32 * w + 24 + rloc) * 1024 + sc8,
      1024, lds, lds + 8192, lds + 16384, lds + 24576, acc);
  const int wm = (w >> 1) * 64, wn = (w & 1) * 64;
  const int lr = lane & 15, lg = lane >> 4;
  const float* bias = (ty ? vb : kb) + (size_t)e * 1024 + nblk * 128;
  u16* Cb = kvbuf + ((size_t)(e * 2 + ty) * 2048 + (size_t)mblk * 128) * 1024 + nblk * 128;
#pragma unroll
  for (int ni = 0; ni < 4; ++ni) {
    int lcol = wn + ni * 16 + lr;
    float bv = bias[lcol];
#pragma unroll
    for (int mi = 0; mi < 4; ++mi)
#pragma unroll
      for (int rg = 0; rg < 4; ++rg) {
        int lrow = wm + mi * 16 + lg * 4 + rg;
        Cb[(size_t)lrow * 1024 + lcol] = f2bf(acc[mi][ni][rg] + bv);
      }
  }
}

// ---------- Q gathered GEMM: qc[p][pos][1024] = xb[tok rows] @ qW_e^T + qb ----------
__global__ __launch_bounds__(256) void q_gemm_kernel(
    const u16* __restrict__ xb, const u16* __restrict__ wb_qkv,
    const float* __restrict__ qb, const u32* __restrict__ tok_list,
    const u32* __restrict__ cnt, u16* __restrict__ qc) {
  __shared__ u16 lds[32768];
  int nblk = blockIdx.x, mt = blockIdx.y, p = blockIdx.z;
  int c = (int)cnt[p];
  if (mt * 128 >= c) return;
  int e = p >> 1, b = p & 1;
  const int t = threadIdx.x, w = t >> 6, lane = t & 63;
  const int rloc = lane >> 3, cloc = lane & 7;
  const int sc8 = (cloc ^ rloc) * 8;
  const u32* tl = tok_list + p * 1024 + mt * 128 + 32 * w + rloc;
  int t0 = (int)(tl[0] & 1023), t1 = (int)(tl[8] & 1023);
  int t2 = (int)(tl[16] & 1023), t3 = (int)(tl[24] & 1023);
  const u16* Ab = xb + (size_t)b * 1024 * 1024 + sc8;
  const u16* B = wb_qkv + (size_t)(e * 3) * 1048576 + (size_t)nblk * 128 * 1024;
  f32x4 acc[4][4];
#pragma unroll
  for (int i = 0; i < 4; ++i)
#pragma unroll
    for (int j = 0; j < 4; ++j) { f32x4 z = {0.f, 0.f, 0.f, 0.f}; acc[i][j] = z; }
  gemm_mainloop_p(
      Ab + (size_t)t0 * 1024, Ab + (size_t)t1 * 1024, Ab + (size_t)t2 * 1024, Ab + (size_t)t3 * 1024,
      B + (size_t)(32 * w + 0 + rloc) * 1024 + sc8, B + (size_t)(32 * w + 8 + rloc) * 1024 + sc8,
      B + (size_t)(32 * w + 16 + rloc) * 1024 + sc8, B + (size_t)(32 * w + 24 + rloc) * 1024 + sc8,
      1024, lds, lds + 8192, lds + 16384, lds + 24576, acc);
  const int wm = (w >> 1) * 64, wn = (w & 1) * 64;
  const int lr = lane & 15, lg = lane >> 4;
  const float* bias = qb + (size_t)e * 1024 + nblk * 128;
  u16* Cb = qc + ((size_t)p * 1024 + (size_t)mt * 128) * 1024 + nblk * 128;
#pragma unroll
  for (int ni = 0; ni < 4; ++ni) {
    int lcol = wn + ni * 16 + lr;
    float bv = bias[lcol];
#pragma unroll
    for (int mi = 0; mi < 4; ++mi)
#pragma unroll
      for (int rg = 0; rg < 4; ++rg) {
        int lrow = wm + mi * 16 + lg * 4 + rg;
        Cb[(size_t)lrow * 1024 + lcol] = f2bf(acc[mi][ni][rg] + bv);
      }
  }
}

// ---------- sparse flash attention: 64 compact Q rows per block ----------
__global__ __launch_bounds__(256) void attn_kernel(
    const u16* __restrict__ qc, const u16* __restrict__ kvbuf,
    const u32* __restrict__ cnt, u16* __restrict__ oc) {
  __shared__ u16 Kl[4096];       // [tok 64][dh 64], XOR-swizzled via source
  __shared__ u32 Vtl[2048];      // [dh 64][tokpair 32], chunk-swizzled
  __shared__ u16 Pl[4096];       // per-wave 1024
  int h = blockIdx.x;
  int p = blockIdx.y >> 3, lt = blockIdx.y & 7;
  int c = (int)cnt[p];
  if (lt * 64 >= c) return;
  int e = p >> 1, b = p & 1;
  const u16* Qb = qc + ((size_t)p * 1024 + (size_t)lt * 64) * 1024 + h * 64;
  const u16* Kg = kvbuf + ((size_t)(e * 2 + 0) * 2048 + (size_t)b * 1024) * 1024 + h * 64;
  const u16* Vg = kvbuf + ((size_t)(e * 2 + 1) * 2048 + (size_t)b * 1024) * 1024 + h * 64;
  u16* Og = oc + ((size_t)p * 1024 + (size_t)lt * 64) * 1024 + h * 64;
  const int t = threadIdx.x, w = t >> 6, lane = t & 63;
  const int lr = lane & 15, lg = lane >> 4;
  const int krow_l = lane >> 3, kc = lane & 7;
  const int s2 = t >> 3, sc3 = t & 7;

  bf16x8 qa0 = *reinterpret_cast<const bf16x8*>(Qb + (size_t)(w * 16 + lr) * 1024 + lg * 8);
  bf16x8 qa1 = *reinterpret_cast<const bf16x8*>(Qb + (size_t)(w * 16 + lr) * 1024 + 32 + lg * 8);

  f32x4 oacc[4];
  float mrun[4], lsum[4];
#pragma unroll
  for (int i = 0; i < 4; ++i) {
    f32x4 z = {0.f, 0.f, 0.f, 0.f}; oacc[i] = z; mrun[i] = -3.4e38f; lsum[i] = 0.f;
  }

  for (int it = 0; it < 16; ++it) {
    int kv0 = it * 64;
#pragma unroll
    for (int r = 0; r < 2; ++r) {
      int row = 16 * w + 8 * r + krow_l;
      gl_lds16(Kg + (size_t)(kv0 + row) * 1024 + (kc ^ (row & 7)) * 8,
               Kl + (16 * w + 8 * r) * 64);
    }
    {
      int4 v0r = *reinterpret_cast<const int4*>(Vg + (size_t)(kv0 + 2 * s2) * 1024 + sc3 * 8);
      int4 v1r = *reinterpret_cast<const int4*>(Vg + (size_t)(kv0 + 2 * s2 + 1) * 1024 + sc3 * 8);
      const u16* v0 = reinterpret_cast<const u16*>(&v0r);
      const u16* v1 = reinterpret_cast<const u16*>(&v1r);
#pragma unroll
      for (int j = 0; j < 8; ++j) {
        int jj = (j + sc3) & 7;
        int d = sc3 * 8 + jj;
        u32 val = (u32)v0[jj] | ((u32)v1[jj] << 16);
        Vtl[d * 32 + (((s2 >> 2) ^ (d & 7)) << 2) + (s2 & 3)] = val;
      }
    }
    __syncthreads();
    f32x4 sv[4];
    __builtin_amdgcn_s_setprio(1);
#pragma unroll
    for (int nt = 0; nt < 4; ++nt) {
      f32x4 z = {0.f, 0.f, 0.f, 0.f};
#pragma unroll
      for (int kk = 0; kk < 2; ++kk) {
        int rk = nt * 16 + lr;
        bf16x8 kf = *reinterpret_cast<const bf16x8*>(Kl + rk * 64 + (((kk * 4 + lg) ^ (rk & 7)) << 3));
        z = mfma16(kk ? qa1 : qa0, kf, z);
      }
      sv[nt] = z * 0.125f;
    }
    __builtin_amdgcn_s_setprio(0);
#pragma unroll
    for (int rg = 0; rg < 4; ++rg) {
      float tm = fmaxf(fmaxf(sv[0][rg], sv[1][rg]), fmaxf(sv[2][rg], sv[3][rg]));
#pragma unroll
      for (int mm = 1; mm < 16; mm <<= 1) tm = fmaxf(tm, __shfl_xor(tm, mm));
      float mn = fmaxf(mrun[rg], tm);
      float al = __expf(mrun[rg] - mn);
      mrun[rg] = mn;
      lsum[rg] *= al;
#pragma unroll
      for (int nt = 0; nt < 4; ++nt) oacc[nt][rg] *= al;
    }
#pragma unroll
    for (int nt = 0; nt < 4; ++nt) {
#pragma unroll
      for (int rg = 0; rg < 4; ++rg) {
        float pv = __expf(sv[nt][rg] - mrun[rg]);
        lsum[rg] += pv;
        int prow = lg * 4 + rg;
        Pl[w * 1024 + prow * 64 + ((nt * 16 + lr) ^ ((prow & 7) << 3))] = f2bf(pv);
      }
    }
    __builtin_amdgcn_s_setprio(1);
#pragma unroll
    for (int kk = 0; kk < 2; ++kk) {
      bf16x8 pf = *reinterpret_cast<const bf16x8*>(
          Pl + w * 1024 + lr * 64 + (((kk * 4 + lg) ^ (lr & 7)) << 3));
#pragma unroll
      for (int nt = 0; nt < 4; ++nt) {
        int rv = nt * 16 + lr;
        bf16x8 vf = *reinterpret_cast<const bf16x8*>(
            reinterpret_cast<const u16*>(Vtl) + rv * 64 + (((kk * 4 + lg) ^ (rv & 7)) << 3));
        oacc[nt] = mfma16(pf, vf, oacc[nt]);
      }
    }
    __builtin_amdgcn_s_setprio(0);
    __syncthreads();
  }
#pragma unroll
  for (int rg = 0; rg < 4; ++rg) {
#pragma unroll
    for (int mm = 1; mm < 16; mm <<= 1) lsum[rg] += __shfl_xor(lsum[rg], mm);
    float inv = 1.0f / lsum[rg];
#pragma unroll
    for (int nt = 0; nt < 4; ++nt)
      Og[(size_t)(w * 16 + lg * 4 + rg) * 1024 + nt * 16 + lr] = f2bf(oacc[nt][rg] * inv);
  }
}

// ---------- output projection (compact rows, no gating, plain stores) ----------
__global__ __launch_bounds__(256) void oproj_kernel(
    const u16* __restrict__ oc, const u16* __restrict__ wb_o,
    const u32* __restrict__ cnt, float* __restrict__ projc) {
  __shared__ u16 lds[32768];
  int nblk = blockIdx.x, mt = blockIdx.y, p = blockIdx.z;
  int c = (int)cnt[p];
  if (mt * 128 >= c) return;
  int e = p >> 1;
  const int t = threadIdx.x, w = t >> 6, lane = t & 63;
  const int rloc = lane >> 3, cloc = lane & 7;
  const int sc8 = (cloc ^ rloc) * 8;
  const u16* A = oc + ((size_t)p * 1024 + (size_t)mt * 128) * 1024;
  const u16* B = wb_o + (size_t)e * 1048576 + (size_t)nblk * 128 * 1024;
  f32x4 acc[4][4];
#pragma unroll
  for (int i = 0; i < 4; ++i)
#pragma unroll
    for (int j = 0; j < 4; ++j) { f32x4 z = {0.f, 0.f, 0.f, 0.f}; acc[i][j] = z; }
  gemm_mainloop_p(
      A + (size_t)(32 * w + 0 + rloc) * 1024 + sc8, A + (size_t)(32 * w + 8 + rloc) * 1024 + sc8,
      A + (size_t)(32 * w + 16 + rloc) * 1024 + sc8, A + (size_t)(32 * w + 24 + rloc) * 1024 + sc8,
      B + (size_t)(32 * w + 0 + rloc) * 1024 + sc8, B + (size_t)(32 * w + 8 + rloc) * 1024 + sc8,
      B + (size_t)(32 * w + 16 + rloc) * 1024 + sc8, B + (size_t)(32 * w + 24 + rloc) * 1024 + sc8,
      1024, lds, lds + 8192, lds + 16384, lds + 24576, acc);
  const int wm = (w >> 1) * 64, wn = (w & 1) * 64;
  const int lr = lane & 15, lg = lane >> 4;
  float* Pb = projc + ((size_t)p * 1024 + (size_t)mt * 128) * 1024 + nblk * 128;
#pragma unroll
  for (int mi = 0; mi < 4; ++mi)
#pragma unroll
    for (int rg = 0; rg < 4; ++rg) {
      int lrow = wm + mi * 16 + lg * 4 + rg;
#pragma unroll
      for (int ni = 0; ni < 4; ++ni) {
        int lcol = wn + ni * 16 + lr;
        Pb[(size_t)lrow * 1024 + lcol] = acc[mi][ni][rg];
      }
    }
}

// ---------- final merge: out[tok] = g1*(projc1+ob1) + g2*(projc2+ob2) ----------
__global__ __launch_bounds__(256) void merge_out(
    const float* __restrict__ projc, const float* __restrict__ ob,
    const float* __restrict__ gate_list, const u32* __restrict__ inv,
    float* __restrict__ out) {
  int tok = blockIdx.x;
  int c4 = threadIdx.x * 4;
  u32 i1 = inv[tok * 2], i2 = inv[tok * 2 + 1];
  int idx1 = (int)(i1 >> 10) * 1024 + (int)(i1 & 1023);
  int idx2 = (int)(i2 >> 10) * 1024 + (int)(i2 & 1023);
  float g1 = gate_list[idx1], g2 = gate_list[idx2];
  int e1 = (int)(i1 >> 11), e2 = (int)(i2 >> 11);
  float4 a = *reinterpret_cast<const float4*>(projc + (size_t)idx1 * 1024 + c4);
  float4 bvec = *reinterpret_cast<const float4*>(projc + (size_t)idx2 * 1024 + c4);
  float4 o1 = *reinterpret_cast<const float4*>(ob + (size_t)e1 * 1024 + c4);
  float4 o2 = *reinterpret_cast<const float4*>(ob + (size_t)e2 * 1024 + c4);
  float4 r;
  r.x = g1 * (a.x + o1.x) + g2 * (bvec.x + o2.x);
  r.y = g1 * (a.y + o1.y) + g2 * (bvec.y + o2.y);
  r.z = g1 * (a.z + o1.z) + g2 * (bvec.z + o2.z);
  r.w = g1 * (a.w + o1.w) + g2 * (bvec.w + o2.w);
  *reinterpret_cast<float4*>(out + (size_t)tok * 1024 + c4) = r;
}

// ---------- host launcher ----------
extern "C" void kernel_launch(void* const* d_in, const int* in_sizes, int n_in,
                              void* d_out, int out_size, void* d_ws, size_t ws_size,
                              hipStream_t stream) {
  const float* x    = (const float*)d_in[0];
  const float* rW1  = (const float*)d_in[1];
  const float* rb1  = (const float*)d_in[2];
  const float* ln_g = (const float*)d_in[3];
  const float* ln_b = (const float*)d_in[4];
  const float* rW2  = (const float*)d_in[5];
  const float* rb2  = (const float*)d_in[6];
  const float* qW   = (const float*)d_in[7];
  const float* qb   = (const float*)d_in[8];
  const float* kW   = (const float*)d_in[9];
  const float* kb   = (const float*)d_in[10];
  const float* vW   = (const float*)d_in[11];
  const float* vb   = (const float*)d_in[12];
  const float* oW   = (const float*)d_in[13];
  const float* ob   = (const float*)d_in[14];
  float* out = (float*)d_out;

  const size_t need = 50331648ull + 16777216ull + 67108864ull + 33554432ull +
                      33554432ull + 4194304ull + 147520ull;
  if (ws_size < need) return;
  char* pp = (char*)d_ws;
  u16* wb_qkv = (u16*)pp; pp += 50331648ull;   // [8][3][1024][1024]
  u16* wb_o   = (u16*)pp; pp += 16777216ull;   // [8][1024][1024]
  u16* kvbuf  = (u16*)pp; pp += 67108864ull;   // [8][2][2048][1024]; projc aliases (64MB)
  u16* qc     = (u16*)pp; pp += 33554432ull;   // [16][1024][1024]
  u16* oc     = (u16*)pp; pp += 33554432ull;   // [16][1024][1024]
  u16* xb     = (u16*)pp; pp += 4194304ull;    // [2048][1024]
  u32* lists  = (u32*)pp;
  u32* tok_list    = lists;                    // 16384
  float* gate_list = (float*)(lists + 16384);  // 16384
  u32* cnt         = lists + 32768;            // 16
  u32* inv         = lists + 32784;            // 4096
  float* hbuf  = (float*)qc;                   // alias (dead before qc written)
  float* projc = (float*)kvbuf;                // alias (dead after attn)

  cvt_x_kernel<<<dim3(2048), dim3(256), 0, stream>>>(x, xb);
  cvt_w_kernel<<<dim3(2048), dim3(256), 0, stream>>>(qW, kW, vW, oW, wb_qkv, wb_o);
  router_gemm1<<<dim3(32, 8), dim3(256), 0, stream>>>(x, rW1, rb1, hbuf);
  zero_lists<<<dim3(129), dim3(256), 0, stream>>>(lists);
  router_finish<<<dim3(2048), dim3(64), 0, stream>>>(hbuf, ln_g, ln_b, rW2, rb2,
                                                     tok_list, gate_list, cnt, inv);
  kv_gemm_kernel<<<dim3(2048), dim3(256), 0, stream>>>(xb, wb_qkv, kb, vb, kvbuf);
  q_gemm_kernel<<<dim3(8, 8, 16), dim3(256), 0, stream>>>(xb, wb_qkv, qb, tok_list, cnt, qc);
  attn_kernel<<<dim3(16, 128), dim3(256), 0, stream>>>(qc, kvbuf, cnt, oc);
  oproj_kernel<<<dim3(8, 8, 16), dim3(256), 0, stream>>>(oc, wb_o, cnt, projc);
  merge_out<<<dim3(2048), dim3(256), 0, stream>>>(projc, ob, gate_list, inv, out);
}

// Round 5
// 485.253 us; speedup vs baseline: 1.5237x; 1.1117x over previous
//
#include <hip/hip_runtime.h>
#include <hip/hip_bf16.h>

typedef unsigned short u16;
typedef unsigned int u32;
typedef __bf16 bf16x8 __attribute__((ext_vector_type(8)));
typedef float f32x4 __attribute__((ext_vector_type(4)));

// ---------- helpers ----------
__device__ __forceinline__ u16 f2bf(float f) {
  union { float f; unsigned u; } v; v.f = f;
  unsigned r = v.u + 0x7fffu + ((v.u >> 16) & 1u);   // RNE
  return (u16)(r >> 16);
}

__device__ __forceinline__ f32x4 mfma16(bf16x8 a, bf16x8 b, f32x4 c) {
  return __builtin_amdgcn_mfma_f32_16x16x32_bf16(a, b, c, 0, 0, 0);
}

// async global->LDS, 16B/lane; LDS dest = wave-uniform base + lane*16
__device__ __forceinline__ void gl_lds16(const u16* g, u16* l) {
  __builtin_amdgcn_global_load_lds(
      (const __attribute__((address_space(1))) u32*)g,
      (__attribute__((address_space(3))) u32*)l, 16, 0, 0);
}

// ---------- bf16 conversion ----------
__global__ __launch_bounds__(256) void cvt_x_kernel(const float* __restrict__ x, u16* __restrict__ xb) {
  size_t i = (size_t)blockIdx.x * 256 + threadIdx.x;     // 524288 float4's
  float4 v = reinterpret_cast<const float4*>(x)[i];
  unsigned long long pk = (unsigned long long)f2bf(v.x) |
                          ((unsigned long long)f2bf(v.y) << 16) |
                          ((unsigned long long)f2bf(v.z) << 32) |
                          ((unsigned long long)f2bf(v.w) << 48);
  *reinterpret_cast<unsigned long long*>(xb + i * 4) = pk;
}

// all 8 experts: wb_qkv [8][3][1024][1024], wb_o [8][1024][1024]
__global__ __launch_bounds__(256) void cvt_w_kernel(
    const float* __restrict__ qW, const float* __restrict__ kW,
    const float* __restrict__ vW, const float* __restrict__ oW,
    u16* __restrict__ wb_qkv, u16* __restrict__ wb_o) {
  const size_t nqkv4 = (size_t)8 * 3 * 262144;
  const size_t total = nqkv4 + (size_t)8 * 262144;
  for (size_t i = (size_t)blockIdx.x * 256 + threadIdx.x; i < total;
       i += (size_t)gridDim.x * 256) {
    const float* src; u16* dst;
    if (i < nqkv4) {
      size_t elem = i * 4;
      size_t blk = elem >> 20;              // e*3 + type
      size_t el = blk / 3, ty = blk % 3;
      const float* W = (ty == 0 ? qW : (ty == 1 ? kW : vW));
      src = W + el * 1048576 + (elem & 1048575);
      dst = wb_qkv + elem;
    } else {
      size_t elem = (i - nqkv4) * 4;
      size_t el = elem >> 20;
      src = oW + el * 1048576 + (elem & 1048575);
      dst = wb_o + elem;
    }
    float4 v = *reinterpret_cast<const float4*>(src);
    unsigned long long pk = (unsigned long long)f2bf(v.x) |
                            ((unsigned long long)f2bf(v.y) << 16) |
                            ((unsigned long long)f2bf(v.z) << 32) |
                            ((unsigned long long)f2bf(v.w) << 48);
    *reinterpret_cast<unsigned long long*>(dst) = pk;
  }
}

// ---------- zero the list buffers (ws poisoned before every call) ----------
__global__ __launch_bounds__(256) void zero_lists(u32* __restrict__ lists) {
  int i = blockIdx.x * 256 + threadIdx.x;
  if (i < 32784) lists[i] = 0;
}

// ---------- router (fp32 for exact top-2 selection) ----------
__global__ __launch_bounds__(256) void router_gemm1(
    const float* __restrict__ x, const float* __restrict__ rW1,
    const float* __restrict__ rb1, float* __restrict__ hbuf) {
  __shared__ float aT[16][72];
  __shared__ float bT[16][72];
  int t = threadIdx.x;
  int tx = t & 15, ty = t >> 4;
  int m0 = blockIdx.x * 64, n0 = blockIdx.y * 64;
  float acc[4][4];
#pragma unroll
  for (int i = 0; i < 4; ++i)
#pragma unroll
    for (int j = 0; j < 4; ++j) acc[i][j] = 0.f;
  const float* Ab = x + (size_t)m0 * 1024;
  const float* Bb = rW1 + (size_t)n0 * 1024;
  int r = t >> 2, c4 = (t & 3) * 4;
  for (int k0 = 0; k0 < 1024; k0 += 16) {
    float4 av = *reinterpret_cast<const float4*>(Ab + (size_t)r * 1024 + k0 + c4);
    float4 bv = *reinterpret_cast<const float4*>(Bb + (size_t)r * 1024 + k0 + c4);
    aT[c4 + 0][r] = av.x; aT[c4 + 1][r] = av.y; aT[c4 + 2][r] = av.z; aT[c4 + 3][r] = av.w;
    bT[c4 + 0][r] = bv.x; bT[c4 + 1][r] = bv.y; bT[c4 + 2][r] = bv.z; bT[c4 + 3][r] = bv.w;
    __syncthreads();
#pragma unroll
    for (int kk = 0; kk < 16; ++kk) {
      float4 a = *reinterpret_cast<const float4*>(&aT[kk][ty * 4]);
      float4 b = *reinterpret_cast<const float4*>(&bT[kk][tx * 4]);
      float aa[4] = {a.x, a.y, a.z, a.w};
      float bb[4] = {b.x, b.y, b.z, b.w};
#pragma unroll
      for (int i = 0; i < 4; ++i)
#pragma unroll
        for (int j = 0; j < 4; ++j) acc[i][j] += aa[i] * bb[j];
    }
    __syncthreads();
  }
#pragma unroll
  for (int i = 0; i < 4; ++i) {
    int row = m0 + ty * 4 + i;
#pragma unroll
    for (int j = 0; j < 4; ++j) {
      int col = n0 + tx * 4 + j;
      hbuf[(size_t)row * 512 + col] = acc[i][j] + rb1[col];
    }
  }
}

__global__ __launch_bounds__(64) void router_finish(
    const float* __restrict__ hbuf, const float* __restrict__ ln_g,
    const float* __restrict__ ln_b, const float* __restrict__ rW2,
    const float* __restrict__ rb2,
    u32* __restrict__ tok_list, float* __restrict__ gate_list,
    u32* __restrict__ cnt, u32* __restrict__ inv) {
  int tok = blockIdx.x, lane = threadIdx.x;
  const float* hr = hbuf + (size_t)tok * 512;
  float4 v0 = *reinterpret_cast<const float4*>(hr + lane * 8);
  float4 v1 = *reinterpret_cast<const float4*>(hr + lane * 8 + 4);
  float hv[8] = {v0.x, v0.y, v0.z, v0.w, v1.x, v1.y, v1.z, v1.w};
  float s = 0.f;
#pragma unroll
  for (int j = 0; j < 8; ++j) s += hv[j];
#pragma unroll
  for (int m = 1; m < 64; m <<= 1) s += __shfl_xor(s, m);
  float mu = s * (1.0f / 512.0f);
  float s2 = 0.f;
#pragma unroll
  for (int j = 0; j < 8; ++j) { float d = hv[j] - mu; s2 += d * d; }
#pragma unroll
  for (int m = 1; m < 64; m <<= 1) s2 += __shfl_xor(s2, m);
  float rstd = 1.0f / sqrtf(s2 * (1.0f / 512.0f) + 1e-5f);
#pragma unroll
  for (int j = 0; j < 8; ++j) {
    float tv = (hv[j] - mu) * rstd * ln_g[lane * 8 + j] + ln_b[lane * 8 + j];
    hv[j] = fmaxf(tv, 0.0f);
  }
  float logit[8];
#pragma unroll
  for (int n = 0; n < 8; ++n) {
    const float* wr = rW2 + (size_t)n * 512 + lane * 8;
    float p = 0.f;
#pragma unroll
    for (int j = 0; j < 8; ++j) p += hv[j] * wr[j];
#pragma unroll
    for (int m = 1; m < 64; m <<= 1) p += __shfl_xor(p, m);
    logit[n] = p + rb2[n];
  }
  int i1 = 0; float l1 = logit[0];
#pragma unroll
  for (int n = 1; n < 8; ++n) if (logit[n] > l1) { l1 = logit[n]; i1 = n; }
  int i2 = -1; float l2 = -3.4e38f;
#pragma unroll
  for (int n = 0; n < 8; ++n) if (n != i1 && logit[n] > l2) { l2 = logit[n]; i2 = n; }
  float e2 = __expf(l2 - l1);
  float g1 = 1.0f / (1.0f + e2);
  float g2 = e2 * g1;
  if (lane == 0) {
    int b = tok >> 10, sq = tok & 1023;
    int p1 = i1 * 2 + b;
    u32 pos1 = atomicAdd(&cnt[p1], 1u);
    tok_list[p1 * 1024 + pos1] = (u32)sq;
    gate_list[p1 * 1024 + pos1] = g1;
    inv[tok * 2 + 0] = ((u32)p1 << 10) | pos1;
    int p2 = i2 * 2 + b;
    u32 pos2 = atomicAdd(&cnt[p2], 1u);
    tok_list[p2 * 1024 + pos2] = (u32)sq;
    gate_list[p2 * 1024 + pos2] = g2;
    inv[tok * 2 + 1] = ((u32)p2 << 10) | pos2;
  }
}

// ---------- 2-phase double-buffered 128x128 bf16 MFMA mainloop ----------
__device__ __forceinline__ void stage8(
    const u16* aS0, const u16* aS1, const u16* aS2, const u16* aS3,
    const u16* bS0, const u16* bS1, const u16* bS2, const u16* bS3,
    int k0, u16* aL, u16* bL, int w) {
  gl_lds16(aS0 + k0, aL + (32 * w + 0) * 64);
  gl_lds16(aS1 + k0, aL + (32 * w + 8) * 64);
  gl_lds16(aS2 + k0, aL + (32 * w + 16) * 64);
  gl_lds16(aS3 + k0, aL + (32 * w + 24) * 64);
  gl_lds16(bS0 + k0, bL + (32 * w + 0) * 64);
  gl_lds16(bS1 + k0, bL + (32 * w + 8) * 64);
  gl_lds16(bS2 + k0, bL + (32 * w + 16) * 64);
  gl_lds16(bS3 + k0, bL + (32 * w + 24) * 64);
}

__device__ __forceinline__ void gemm_mainloop_p(
    const u16* aS0, const u16* aS1, const u16* aS2, const u16* aS3,
    const u16* bS0, const u16* bS1, const u16* bS2, const u16* bS3,
    int K, u16* aL0, u16* bL0, u16* aL1, u16* bL1, f32x4 acc[4][4]) {
  const int t = threadIdx.x;
  const int w = t >> 6, lane = t & 63;
  const int wm = (w >> 1) * 64, wn = (w & 1) * 64;
  const int lr = lane & 15, lg = lane >> 4;
  const int T = K >> 6;
  stage8(aS0, aS1, aS2, aS3, bS0, bS1, bS2, bS3, 0, aL0, bL0, w);
  __syncthreads();
  for (int tt = 0; tt < T; ++tt) {
    u16* aC = (tt & 1) ? aL1 : aL0;
    u16* bC = (tt & 1) ? bL1 : bL0;
    if (tt + 1 < T) {
      u16* aN = (tt & 1) ? aL0 : aL1;
      u16* bN = (tt & 1) ? bL0 : bL1;
      stage8(aS0, aS1, aS2, aS3, bS0, bS1, bS2, bS3, (tt + 1) << 6, aN, bN, w);
    }
    __builtin_amdgcn_s_setprio(1);
#pragma unroll
    for (int kk = 0; kk < 2; ++kk) {
      bf16x8 af[4], bfr[4];
#pragma unroll
      for (int i = 0; i < 4; ++i) {
        int ra = wm + i * 16 + lr;
        af[i] = *reinterpret_cast<const bf16x8*>(aC + ra * 64 + (((kk * 4 + lg) ^ (ra & 7)) << 3));
        int rb = wn + i * 16 + lr;
        bfr[i] = *reinterpret_cast<const bf16x8*>(bC + rb * 64 + (((kk * 4 + lg) ^ (rb & 7)) << 3));
      }
#pragma unroll
      for (int mi = 0; mi < 4; ++mi)
#pragma unroll
        for (int ni = 0; ni < 4; ++ni)
          acc[mi][ni] = mfma16(af[mi], bfr[ni], acc[mi][ni]);
    }
    __builtin_amdgcn_s_setprio(0);
    __syncthreads();
  }
}

// ---------- K + V^T GEMMs: kbuf[e][2048][1024]; vtbuf[e][2][1024 d][1024 tok] ----------
__global__ __launch_bounds__(256) void kv_gemm_kernel(
    const u16* __restrict__ xb, const u16* __restrict__ wb_qkv,
    const float* __restrict__ kb, const float* __restrict__ vb,
    u16* __restrict__ kbuf, u16* __restrict__ vtbuf) {
  __shared__ u16 lds[32768];
  int orig = blockIdx.x;                         // 2048, %8==0
  int wgid = (orig & 7) * 256 + (orig >> 3);     // XCD-bijective swizzle
  int e = wgid >> 8, r = wgid & 255;
  int ty = r >> 7, rr = r & 127;
  const int t = threadIdx.x, w = t >> 6, lane = t & 63;
  const int rloc = lane >> 3, cloc = lane & 7;
  const int sc8 = (cloc ^ rloc) * 8;
  const u16 *A, *B;
  int mblk, nblk;
  if (ty == 0) {            // K: A = xb tokens, B = kW rows
    mblk = rr >> 3; nblk = rr & 7;
    A = xb + (size_t)mblk * 128 * 1024;
    B = wb_qkv + (size_t)(e * 3 + 1) * 1048576 + (size_t)nblk * 128 * 1024;
  } else {                  // V^T: A = vW rows (d), B = xb tokens
    mblk = rr & 7; nblk = rr >> 3;
    A = wb_qkv + (size_t)(e * 3 + 2) * 1048576 + (size_t)mblk * 128 * 1024;
    B = xb + (size_t)nblk * 128 * 1024;
  }
  f32x4 acc[4][4];
#pragma unroll
  for (int i = 0; i < 4; ++i)
#pragma unroll
    for (int j = 0; j < 4; ++j) { f32x4 z = {0.f, 0.f, 0.f, 0.f}; acc[i][j] = z; }
  gemm_mainloop_p(
      A + (size_t)(32 * w + 0 + rloc) * 1024 + sc8, A + (size_t)(32 * w + 8 + rloc) * 1024 + sc8,
      A + (size_t)(32 * w + 16 + rloc) * 1024 + sc8, A + (size_t)(32 * w + 24 + rloc) * 1024 + sc8,
      B + (size_t)(32 * w + 0 + rloc) * 1024 + sc8, B + (size_t)(32 * w + 8 + rloc) * 1024 + sc8,
      B + (size_t)(32 * w + 16 + rloc) * 1024 + sc8, B + (size_t)(32 * w + 24 + rloc) * 1024 + sc8,
      1024, lds, lds + 8192, lds + 16384, lds + 24576, acc);
  const int wm = (w >> 1) * 64, wn = (w & 1) * 64;
  const int lr = lane & 15, lg = lane >> 4;
  if (ty == 0) {
    const float* bias = kb + (size_t)e * 1024 + nblk * 128;
    u16* Cb = kbuf + ((size_t)e * 2048 + (size_t)mblk * 128) * 1024 + nblk * 128;
#pragma unroll
    for (int ni = 0; ni < 4; ++ni) {
      int lcol = wn + ni * 16 + lr;
      float bv = bias[lcol];
#pragma unroll
      for (int mi = 0; mi < 4; ++mi)
#pragma unroll
        for (int rg = 0; rg < 4; ++rg) {
          int lrow = wm + mi * 16 + lg * 4 + rg;
          Cb[(size_t)lrow * 1024 + lcol] = f2bf(acc[mi][ni][rg] + bv);
        }
    }
  } else {
    const float* bias = vb + (size_t)e * 1024 + mblk * 128;   // bias along rows (d)
    int bb = nblk >> 3, nn = nblk & 7;
    u16* Cb = vtbuf + ((size_t)(e * 2 + bb) * 1024 + (size_t)mblk * 128) * 1024 + nn * 128;
#pragma unroll
    for (int ni = 0; ni < 4; ++ni) {
      int lcol = wn + ni * 16 + lr;
#pragma unroll
      for (int mi = 0; mi < 4; ++mi)
#pragma unroll
        for (int rg = 0; rg < 4; ++rg) {
          int lrow = wm + mi * 16 + lg * 4 + rg;
          Cb[(size_t)lrow * 1024 + lcol] = f2bf(acc[mi][ni][rg] + bias[lrow]);
        }
    }
  }
}

// ---------- Q gathered GEMM: qc[p][pos][1024] = xb[tok rows] @ qW_e^T + qb ----------
__global__ __launch_bounds__(256) void q_gemm_kernel(
    const u16* __restrict__ xb, const u16* __restrict__ wb_qkv,
    const float* __restrict__ qb, const u32* __restrict__ tok_list,
    const u32* __restrict__ cnt, u16* __restrict__ qc) {
  __shared__ u16 lds[32768];
  int nblk = blockIdx.x, mt = blockIdx.y, p = blockIdx.z;
  int c = (int)cnt[p];
  if (mt * 128 >= c) return;
  int e = p >> 1, b = p & 1;
  const int t = threadIdx.x, w = t >> 6, lane = t & 63;
  const int rloc = lane >> 3, cloc = lane & 7;
  const int sc8 = (cloc ^ rloc) * 8;
  const u32* tl = tok_list + p * 1024 + mt * 128 + 32 * w + rloc;
  int t0 = (int)(tl[0] & 1023), t1 = (int)(tl[8] & 1023);
  int t2 = (int)(tl[16] & 1023), t3 = (int)(tl[24] & 1023);
  const u16* Ab = xb + (size_t)b * 1024 * 1024 + sc8;
  const u16* B = wb_qkv + (size_t)(e * 3) * 1048576 + (size_t)nblk * 128 * 1024;
  f32x4 acc[4][4];
#pragma unroll
  for (int i = 0; i < 4; ++i)
#pragma unroll
    for (int j = 0; j < 4; ++j) { f32x4 z = {0.f, 0.f, 0.f, 0.f}; acc[i][j] = z; }
  gemm_mainloop_p(
      Ab + (size_t)t0 * 1024, Ab + (size_t)t1 * 1024, Ab + (size_t)t2 * 1024, Ab + (size_t)t3 * 1024,
      B + (size_t)(32 * w + 0 + rloc) * 1024 + sc8, B + (size_t)(32 * w + 8 + rloc) * 1024 + sc8,
      B + (size_t)(32 * w + 16 + rloc) * 1024 + sc8, B + (size_t)(32 * w + 24 + rloc) * 1024 + sc8,
      1024, lds, lds + 8192, lds + 16384, lds + 24576, acc);
  const int wm = (w >> 1) * 64, wn = (w & 1) * 64;
  const int lr = lane & 15, lg = lane >> 4;
  const float* bias = qb + (size_t)e * 1024 + nblk * 128;
  u16* Cb = qc + ((size_t)p * 1024 + (size_t)mt * 128) * 1024 + nblk * 128;
#pragma unroll
  for (int ni = 0; ni < 4; ++ni) {
    int lcol = wn + ni * 16 + lr;
    float bv = bias[lcol];
#pragma unroll
    for (int mi = 0; mi < 4; ++mi)
#pragma unroll
      for (int rg = 0; rg < 4; ++rg) {
        int lrow = wm + mi * 16 + lg * 4 + rg;
        Cb[(size_t)lrow * 1024 + lcol] = f2bf(acc[mi][ni][rg] + bv);
      }
  }
}

// ---------- sparse flash attention: dbuf async K + Vt staging ----------
__global__ __launch_bounds__(256) void attn_kernel(
    const u16* __restrict__ qc, const u16* __restrict__ kbuf,
    const u16* __restrict__ vtbuf, const u32* __restrict__ cnt,
    u16* __restrict__ oc) {
  __shared__ u16 Kl[2][4096];    // [buf][tok 64][dh 64], source pre-swizzled
  __shared__ u16 Vtl[2][4096];   // [buf][dh 64][tok 64], source pre-swizzled
  __shared__ u16 Pl[4096];       // per-wave 1024
  int h = blockIdx.x;
  int p = blockIdx.y >> 3, lt = blockIdx.y & 7;
  int c = (int)cnt[p];
  if (lt * 64 >= c) return;
  int e = p >> 1, b = p & 1;
  const u16* Qb = qc + ((size_t)p * 1024 + (size_t)lt * 64) * 1024 + h * 64;
  const u16* Kg = kbuf + ((size_t)e * 2048 + (size_t)b * 1024) * 1024 + h * 64;
  const u16* Vtg = vtbuf + ((size_t)(e * 2 + b) * 1024 + (size_t)h * 64) * 1024;
  u16* Og = oc + ((size_t)p * 1024 + (size_t)lt * 64) * 1024 + h * 64;
  const int t = threadIdx.x, w = t >> 6, lane = t & 63;
  const int lr = lane & 15, lg = lane >> 4;
  const int rloc = lane >> 3, kc = lane & 7;

  // stage tile `it` of K and Vt into buffers (wave w covers rows 16w..16w+15)
  // K row = token (kv0+row), col pre-swizzled; Vt row = d, cols = tokens kv0..
#define STAGE_ATTN(IT, KB, VB)                                                   \
  {                                                                              \
    int kv0_ = (IT) * 64;                                                        \
    _Pragma("unroll")                                                            \
    for (int r_ = 0; r_ < 2; ++r_) {                                             \
      int row_ = 16 * w + 8 * r_ + rloc;                                         \
      gl_lds16(Kg + (size_t)(kv0_ + row_) * 1024 + (kc ^ (row_ & 7)) * 8,        \
               (KB) + (16 * w + 8 * r_) * 64);                                   \
      gl_lds16(Vtg + (size_t)row_ * 1024 + kv0_ + (kc ^ (row_ & 7)) * 8,         \
               (VB) + (16 * w + 8 * r_) * 64);                                   \
    }                                                                            \
  }

  STAGE_ATTN(0, Kl[0], Vtl[0]);

  bf16x8 qa0 = *reinterpret_cast<const bf16x8*>(Qb + (size_t)(w * 16 + lr) * 1024 + lg * 8);
  bf16x8 qa1 = *reinterpret_cast<const bf16x8*>(Qb + (size_t)(w * 16 + lr) * 1024 + 32 + lg * 8);

  f32x4 oacc[4];
  float mrun[4], lsum[4];
#pragma unroll
  for (int i = 0; i < 4; ++i) {
    f32x4 z = {0.f, 0.f, 0.f, 0.f}; oacc[i] = z; mrun[i] = -3.4e38f; lsum[i] = 0.f;
  }
  __syncthreads();   // tile 0 resident

  for (int it = 0; it < 16; ++it) {
    const int cur = it & 1;
    const u16* Kc = Kl[cur];
    const u16* Vc = Vtl[cur];
    if (it + 1 < 16) STAGE_ATTN(it + 1, Kl[cur ^ 1], Vtl[cur ^ 1]);
    // ---- QK^T ----
    f32x4 sv[4];
    __builtin_amdgcn_s_setprio(1);
#pragma unroll
    for (int nt = 0; nt < 4; ++nt) {
      f32x4 z = {0.f, 0.f, 0.f, 0.f};
#pragma unroll
      for (int kk = 0; kk < 2; ++kk) {
        int rk = nt * 16 + lr;
        bf16x8 kf = *reinterpret_cast<const bf16x8*>(Kc + rk * 64 + (((kk * 4 + lg) ^ (rk & 7)) << 3));
        z = mfma16(kk ? qa1 : qa0, kf, z);
      }
      sv[nt] = z * 0.125f;
    }
    __builtin_amdgcn_s_setprio(0);
    // ---- online softmax ----
#pragma unroll
    for (int rg = 0; rg < 4; ++rg) {
      float tm = fmaxf(fmaxf(sv[0][rg], sv[1][rg]), fmaxf(sv[2][rg], sv[3][rg]));
#pragma unroll
      for (int mm = 1; mm < 16; mm <<= 1) tm = fmaxf(tm, __shfl_xor(tm, mm));
      float mn = fmaxf(mrun[rg], tm);
      float al = __expf(mrun[rg] - mn);
      mrun[rg] = mn;
      lsum[rg] *= al;
#pragma unroll
      for (int nt = 0; nt < 4; ++nt) oacc[nt][rg] *= al;
    }
#pragma unroll
    for (int nt = 0; nt < 4; ++nt) {
#pragma unroll
      for (int rg = 0; rg < 4; ++rg) {
        float pv = __expf(sv[nt][rg] - mrun[rg]);
        lsum[rg] += pv;
        int prow = lg * 4 + rg;
        Pl[w * 1024 + prow * 64 + ((nt * 16 + lr) ^ ((prow & 7) << 3))] = f2bf(pv);
      }
    }
    // ---- PV ----
    __builtin_amdgcn_s_setprio(1);
#pragma unroll
    for (int kk = 0; kk < 2; ++kk) {
      bf16x8 pf = *reinterpret_cast<const bf16x8*>(
          Pl + w * 1024 + lr * 64 + (((kk * 4 + lg) ^ (lr & 7)) << 3));
#pragma unroll
      for (int nt = 0; nt < 4; ++nt) {
        int rv = nt * 16 + lr;
        bf16x8 vf = *reinterpret_cast<const bf16x8*>(Vc + rv * 64 + (((kk * 4 + lg) ^ (rv & 7)) << 3));
        oacc[nt] = mfma16(pf, vf, oacc[nt]);
      }
    }
    __builtin_amdgcn_s_setprio(0);
    __syncthreads();   // drains prefetch vmcnt; buffers swap safely
  }
#pragma unroll
  for (int rg = 0; rg < 4; ++rg) {
#pragma unroll
    for (int mm = 1; mm < 16; mm <<= 1) lsum[rg] += __shfl_xor(lsum[rg], mm);
    float inv = 1.0f / lsum[rg];
#pragma unroll
    for (int nt = 0; nt < 4; ++nt)
      Og[(size_t)(w * 16 + lg * 4 + rg) * 1024 + nt * 16 + lr] = f2bf(oacc[nt][rg] * inv);
  }
#undef STAGE_ATTN
}

// ---------- output projection (compact rows, plain stores) ----------
__global__ __launch_bounds__(256) void oproj_kernel(
    const u16* __restrict__ oc, const u16* __restrict__ wb_o,
    const u32* __restrict__ cnt, float* __restrict__ projc) {
  __shared__ u16 lds[32768];
  int nblk = blockIdx.x, mt = blockIdx.y, p = blockIdx.z;
  int c = (int)cnt[p];
  if (mt * 128 >= c) return;
  int e = p >> 1;
  const int t = threadIdx.x, w = t >> 6, lane = t & 63;
  const int rloc = lane >> 3, cloc = lane & 7;
  const int sc8 = (cloc ^ rloc) * 8;
  const u16* A = oc + ((size_t)p * 1024 + (size_t)mt * 128) * 1024;
  const u16* B = wb_o + (size_t)e * 1048576 + (size_t)nblk * 128 * 1024;
  f32x4 acc[4][4];
#pragma unroll
  for (int i = 0; i < 4; ++i)
#pragma unroll
    for (int j = 0; j < 4; ++j) { f32x4 z = {0.f, 0.f, 0.f, 0.f}; acc[i][j] = z; }
  gemm_mainloop_p(
      A + (size_t)(32 * w + 0 + rloc) * 1024 + sc8, A + (size_t)(32 * w + 8 + rloc) * 1024 + sc8,
      A + (size_t)(32 * w + 16 + rloc) * 1024 + sc8, A + (size_t)(32 * w + 24 + rloc) * 1024 + sc8,
      B + (size_t)(32 * w + 0 + rloc) * 1024 + sc8, B + (size_t)(32 * w + 8 + rloc) * 1024 + sc8,
      B + (size_t)(32 * w + 16 + rloc) * 1024 + sc8, B + (size_t)(32 * w + 24 + rloc) * 1024 + sc8,
      1024, lds, lds + 8192, lds + 16384, lds + 24576, acc);
  const int wm = (w >> 1) * 64, wn = (w & 1) * 64;
  const int lr = lane & 15, lg = lane >> 4;
  float* Pb = projc + ((size_t)p * 1024 + (size_t)mt * 128) * 1024 + nblk * 128;
#pragma unroll
  for (int mi = 0; mi < 4; ++mi)
#pragma unroll
    for (int rg = 0; rg < 4; ++rg) {
      int lrow = wm + mi * 16 + lg * 4 + rg;
#pragma unroll
      for (int ni = 0; ni < 4; ++ni) {
        int lcol = wn + ni * 16 + lr;
        Pb[(size_t)lrow * 1024 + lcol] = acc[mi][ni][rg];
      }
    }
}

// ---------- final merge: out[tok] = g1*(projc1+ob1) + g2*(projc2+ob2) ----------
__global__ __launch_bounds__(256) void merge_out(
    const float* __restrict__ projc, const float* __restrict__ ob,
    const float* __restrict__ gate_list, const u32* __restrict__ inv,
    float* __restrict__ out) {
  int tok = blockIdx.x;
  int c4 = threadIdx.x * 4;
  u32 i1 = inv[tok * 2], i2 = inv[tok * 2 + 1];
  int idx1 = (int)(i1 >> 10) * 1024 + (int)(i1 & 1023);
  int idx2 = (int)(i2 >> 10) * 1024 + (int)(i2 & 1023);
  float g1 = gate_list[idx1], g2 = gate_list[idx2];
  int e1 = (int)(i1 >> 11), e2 = (int)(i2 >> 11);
  float4 a = *reinterpret_cast<const float4*>(projc + (size_t)idx1 * 1024 + c4);
  float4 bvec = *reinterpret_cast<const float4*>(projc + (size_t)idx2 * 1024 + c4);
  float4 o1 = *reinterpret_cast<const float4*>(ob + (size_t)e1 * 1024 + c4);
  float4 o2 = *reinterpret_cast<const float4*>(ob + (size_t)e2 * 1024 + c4);
  float4 r;
  r.x = g1 * (a.x + o1.x) + g2 * (bvec.x + o2.x);
  r.y = g1 * (a.y + o1.y) + g2 * (bvec.y + o2.y);
  r.z = g1 * (a.z + o1.z) + g2 * (bvec.z + o2.z);
  r.w = g1 * (a.w + o1.w) + g2 * (bvec.w + o2.w);
  *reinterpret_cast<float4*>(out + (size_t)tok * 1024 + c4) = r;
}

// ---------- host launcher ----------
extern "C" void kernel_launch(void* const* d_in, const int* in_sizes, int n_in,
                              void* d_out, int out_size, void* d_ws, size_t ws_size,
                              hipStream_t stream) {
  const float* x    = (const float*)d_in[0];
  const float* rW1  = (const float*)d_in[1];
  const float* rb1  = (const float*)d_in[2];
  const float* ln_g = (const float*)d_in[3];
  const float* ln_b = (const float*)d_in[4];
  const float* rW2  = (const float*)d_in[5];
  const float* rb2  = (const float*)d_in[6];
  const float* qW   = (const float*)d_in[7];
  const float* qb   = (const float*)d_in[8];
  const float* kW   = (const float*)d_in[9];
  const float* kb   = (const float*)d_in[10];
  const float* vW   = (const float*)d_in[11];
  const float* vb   = (const float*)d_in[12];
  const float* oW   = (const float*)d_in[13];
  const float* ob   = (const float*)d_in[14];
  float* out = (float*)d_out;

  const size_t need = 50331648ull + 16777216ull + 67108864ull + 33554432ull +
                      33554432ull + 4194304ull + 147520ull;
  if (ws_size < need) return;
  char* pp = (char*)d_ws;
  u16* wb_qkv = (u16*)pp; pp += 50331648ull;   // [8][3][1024][1024]
  u16* wb_o   = (u16*)pp; pp += 16777216ull;   // [8][1024][1024]
  u16* kbuf   = (u16*)pp; pp += 33554432ull;   // [8][2048][1024]
  u16* vtbuf  = (u16*)pp; pp += 33554432ull;   // [8][2][1024 d][1024 tok]
  u16* qc     = (u16*)pp; pp += 33554432ull;   // [16][1024][1024]
  u16* oc     = (u16*)pp; pp += 33554432ull;   // [16][1024][1024]
  u16* xb     = (u16*)pp; pp += 4194304ull;    // [2048][1024]
  u32* lists  = (u32*)pp;
  u32* tok_list    = lists;                    // 16384
  float* gate_list = (float*)(lists + 16384);  // 16384
  u32* cnt         = lists + 32768;            // 16
  u32* inv         = lists + 32784;            // 4096
  float* hbuf  = (float*)qc;                   // alias (dead before qc written)
  float* projc = (float*)kbuf;                 // alias kbuf+vtbuf (dead after attn)

  cvt_x_kernel<<<dim3(2048), dim3(256), 0, stream>>>(x, xb);
  cvt_w_kernel<<<dim3(2048), dim3(256), 0, stream>>>(qW, kW, vW, oW, wb_qkv, wb_o);
  router_gemm1<<<dim3(32, 8), dim3(256), 0, stream>>>(x, rW1, rb1, hbuf);
  zero_lists<<<dim3(129), dim3(256), 0, stream>>>(lists);
  router_finish<<<dim3(2048), dim3(64), 0, stream>>>(hbuf, ln_g, ln_b, rW2, rb2,
                                                     tok_list, gate_list, cnt, inv);
  kv_gemm_kernel<<<dim3(2048), dim3(256), 0, stream>>>(xb, wb_qkv, kb, vb, kbuf, vtbuf);
  q_gemm_kernel<<<dim3(8, 8, 16), dim3(256), 0, stream>>>(xb, wb_qkv, qb, tok_list, cnt, qc);
  attn_kernel<<<dim3(16, 128), dim3(256), 0, stream>>>(qc, kbuf, vtbuf, cnt, oc);
  oproj_kernel<<<dim3(8, 8, 16), dim3(256), 0, stream>>>(oc, wb_o, cnt, projc);
  merge_out<<<dim3(2048), dim3(256), 0, stream>>>(projc, ob, gate_list, inv, out);
}

// Round 6
// 480.835 us; speedup vs baseline: 1.5377x; 1.0092x over previous
//
#include <hip/hip_runtime.h>
#include <hip/hip_bf16.h>

typedef unsigned short u16;
typedef unsigned int u32;
typedef __bf16 bf16x8 __attribute__((ext_vector_type(8)));
typedef float f32x4 __attribute__((ext_vector_type(4)));

// ---------- helpers ----------
__device__ __forceinline__ u16 f2bf(float f) {
  union { float f; unsigned u; } v; v.f = f;
  unsigned r = v.u + 0x7fffu + ((v.u >> 16) & 1u);   // RNE
  return (u16)(r >> 16);
}

__device__ __forceinline__ f32x4 mfma16(bf16x8 a, bf16x8 b, f32x4 c) {
  return __builtin_amdgcn_mfma_f32_16x16x32_bf16(a, b, c, 0, 0, 0);
}

// async global->LDS, 16B/lane; LDS dest = wave-uniform base + lane*16
__device__ __forceinline__ void gl_lds16(const u16* g, u16* l) {
  __builtin_amdgcn_global_load_lds(
      (const __attribute__((address_space(1))) u32*)g,
      (__attribute__((address_space(3))) u32*)l, 16, 0, 0);
}

// ---------- bf16 conversion (+ fused list zeroing) ----------
__global__ __launch_bounds__(256) void cvt_x_kernel(const float* __restrict__ x,
                                                    u16* __restrict__ xb,
                                                    u32* __restrict__ lists) {
  size_t i = (size_t)blockIdx.x * 256 + threadIdx.x;     // 524288 float4's
  if (i < 32784) lists[i] = 0;      // tok 16384 + gate 16384 + cnt 16
  float4 v = reinterpret_cast<const float4*>(x)[i];
  unsigned long long pk = (unsigned long long)f2bf(v.x) |
                          ((unsigned long long)f2bf(v.y) << 16) |
                          ((unsigned long long)f2bf(v.z) << 32) |
                          ((unsigned long long)f2bf(v.w) << 48);
  *reinterpret_cast<unsigned long long*>(xb + i * 4) = pk;
}

// all 8 experts: wb_qkv [8][3][1024][1024], wb_o [8][1024][1024]
__global__ __launch_bounds__(256) void cvt_w_kernel(
    const float* __restrict__ qW, const float* __restrict__ kW,
    const float* __restrict__ vW, const float* __restrict__ oW,
    u16* __restrict__ wb_qkv, u16* __restrict__ wb_o) {
  const size_t nqkv4 = (size_t)8 * 3 * 262144;
  const size_t total = nqkv4 + (size_t)8 * 262144;
  for (size_t i = (size_t)blockIdx.x * 256 + threadIdx.x; i < total;
       i += (size_t)gridDim.x * 256) {
    const float* src; u16* dst;
    if (i < nqkv4) {
      size_t elem = i * 4;
      size_t blk = elem >> 20;              // e*3 + type
      size_t el = blk / 3, ty = blk % 3;
      const float* W = (ty == 0 ? qW : (ty == 1 ? kW : vW));
      src = W + el * 1048576 + (elem & 1048575);
      dst = wb_qkv + elem;
    } else {
      size_t elem = (i - nqkv4) * 4;
      size_t el = elem >> 20;
      src = oW + el * 1048576 + (elem & 1048575);
      dst = wb_o + elem;
    }
    float4 v = *reinterpret_cast<const float4*>(src);
    unsigned long long pk = (unsigned long long)f2bf(v.x) |
                            ((unsigned long long)f2bf(v.y) << 16) |
                            ((unsigned long long)f2bf(v.z) << 32) |
                            ((unsigned long long)f2bf(v.w) << 48);
    *reinterpret_cast<unsigned long long*>(dst) = pk;
  }
}

// ---------- router (fp32 for exact top-2 selection) ----------
__global__ __launch_bounds__(256) void router_gemm1(
    const float* __restrict__ x, const float* __restrict__ rW1,
    const float* __restrict__ rb1, float* __restrict__ hbuf) {
  __shared__ float aT[32][72];
  __shared__ float bT[32][72];
  int t = threadIdx.x;
  int tx = t & 15, ty = t >> 4;
  int m0 = blockIdx.x * 64, n0 = blockIdx.y * 64;
  float acc[4][4];
#pragma unroll
  for (int i = 0; i < 4; ++i)
#pragma unroll
    for (int j = 0; j < 4; ++j) acc[i][j] = 0.f;
  const float* Ab = x + (size_t)m0 * 1024;
  const float* Bb = rW1 + (size_t)n0 * 1024;
  int r = t >> 2, c8 = (t & 3) * 8;
  for (int k0 = 0; k0 < 1024; k0 += 32) {
    float4 av0 = *reinterpret_cast<const float4*>(Ab + (size_t)r * 1024 + k0 + c8);
    float4 av1 = *reinterpret_cast<const float4*>(Ab + (size_t)r * 1024 + k0 + c8 + 4);
    float4 bv0 = *reinterpret_cast<const float4*>(Bb + (size_t)r * 1024 + k0 + c8);
    float4 bv1 = *reinterpret_cast<const float4*>(Bb + (size_t)r * 1024 + k0 + c8 + 4);
    aT[c8 + 0][r] = av0.x; aT[c8 + 1][r] = av0.y; aT[c8 + 2][r] = av0.z; aT[c8 + 3][r] = av0.w;
    aT[c8 + 4][r] = av1.x; aT[c8 + 5][r] = av1.y; aT[c8 + 6][r] = av1.z; aT[c8 + 7][r] = av1.w;
    bT[c8 + 0][r] = bv0.x; bT[c8 + 1][r] = bv0.y; bT[c8 + 2][r] = bv0.z; bT[c8 + 3][r] = bv0.w;
    bT[c8 + 4][r] = bv1.x; bT[c8 + 5][r] = bv1.y; bT[c8 + 6][r] = bv1.z; bT[c8 + 7][r] = bv1.w;
    __syncthreads();
#pragma unroll
    for (int kk = 0; kk < 32; ++kk) {
      float4 a = *reinterpret_cast<const float4*>(&aT[kk][ty * 4]);
      float4 b = *reinterpret_cast<const float4*>(&bT[kk][tx * 4]);
      float aa[4] = {a.x, a.y, a.z, a.w};
      float bb[4] = {b.x, b.y, b.z, b.w};
#pragma unroll
      for (int i = 0; i < 4; ++i)
#pragma unroll
        for (int j = 0; j < 4; ++j) acc[i][j] += aa[i] * bb[j];
    }
    __syncthreads();
  }
#pragma unroll
  for (int i = 0; i < 4; ++i) {
    int row = m0 + ty * 4 + i;
#pragma unroll
    for (int j = 0; j < 4; ++j) {
      int col = n0 + tx * 4 + j;
      hbuf[(size_t)row * 512 + col] = acc[i][j] + rb1[col];
    }
  }
}

__global__ __launch_bounds__(64) void router_finish(
    const float* __restrict__ hbuf, const float* __restrict__ ln_g,
    const float* __restrict__ ln_b, const float* __restrict__ rW2,
    const float* __restrict__ rb2,
    u32* __restrict__ tok_list, float* __restrict__ gate_list,
    u32* __restrict__ cnt, u32* __restrict__ inv) {
  int tok = blockIdx.x, lane = threadIdx.x;
  const float* hr = hbuf + (size_t)tok * 512;
  float4 v0 = *reinterpret_cast<const float4*>(hr + lane * 8);
  float4 v1 = *reinterpret_cast<const float4*>(hr + lane * 8 + 4);
  float hv[8] = {v0.x, v0.y, v0.z, v0.w, v1.x, v1.y, v1.z, v1.w};
  float s = 0.f;
#pragma unroll
  for (int j = 0; j < 8; ++j) s += hv[j];
#pragma unroll
  for (int m = 1; m < 64; m <<= 1) s += __shfl_xor(s, m);
  float mu = s * (1.0f / 512.0f);
  float s2 = 0.f;
#pragma unroll
  for (int j = 0; j < 8; ++j) { float d = hv[j] - mu; s2 += d * d; }
#pragma unroll
  for (int m = 1; m < 64; m <<= 1) s2 += __shfl_xor(s2, m);
  float rstd = 1.0f / sqrtf(s2 * (1.0f / 512.0f) + 1e-5f);
#pragma unroll
  for (int j = 0; j < 8; ++j) {
    float tv = (hv[j] - mu) * rstd * ln_g[lane * 8 + j] + ln_b[lane * 8 + j];
    hv[j] = fmaxf(tv, 0.0f);
  }
  float logit[8];
#pragma unroll
  for (int n = 0; n < 8; ++n) {
    const float* wr = rW2 + (size_t)n * 512 + lane * 8;
    float p = 0.f;
#pragma unroll
    for (int j = 0; j < 8; ++j) p += hv[j] * wr[j];
#pragma unroll
    for (int m = 1; m < 64; m <<= 1) p += __shfl_xor(p, m);
    logit[n] = p + rb2[n];
  }
  int i1 = 0; float l1 = logit[0];
#pragma unroll
  for (int n = 1; n < 8; ++n) if (logit[n] > l1) { l1 = logit[n]; i1 = n; }
  int i2 = -1; float l2 = -3.4e38f;
#pragma unroll
  for (int n = 0; n < 8; ++n) if (n != i1 && logit[n] > l2) { l2 = logit[n]; i2 = n; }
  float e2 = __expf(l2 - l1);
  float g1 = 1.0f / (1.0f + e2);
  float g2 = e2 * g1;
  if (lane == 0) {
    int b = tok >> 10, sq = tok & 1023;
    int p1 = i1 * 2 + b;
    u32 pos1 = atomicAdd(&cnt[p1], 1u);
    tok_list[p1 * 1024 + pos1] = (u32)sq;
    gate_list[p1 * 1024 + pos1] = g1;
    inv[tok * 2 + 0] = ((u32)p1 << 10) | pos1;
    int p2 = i2 * 2 + b;
    u32 pos2 = atomicAdd(&cnt[p2], 1u);
    tok_list[p2 * 1024 + pos2] = (u32)sq;
    gate_list[p2 * 1024 + pos2] = g2;
    inv[tok * 2 + 1] = ((u32)p2 << 10) | pos2;
  }
}

// ---------- 2-phase double-buffered 128x128 bf16 MFMA mainloop ----------
__device__ __forceinline__ void stage8(
    const u16* aS0, const u16* aS1, const u16* aS2, const u16* aS3,
    const u16* bS0, const u16* bS1, const u16* bS2, const u16* bS3,
    int k0, u16* aL, u16* bL, int w) {
  gl_lds16(aS0 + k0, aL + (32 * w + 0) * 64);
  gl_lds16(aS1 + k0, aL + (32 * w + 8) * 64);
  gl_lds16(aS2 + k0, aL + (32 * w + 16) * 64);
  gl_lds16(aS3 + k0, aL + (32 * w + 24) * 64);
  gl_lds16(bS0 + k0, bL + (32 * w + 0) * 64);
  gl_lds16(bS1 + k0, bL + (32 * w + 8) * 64);
  gl_lds16(bS2 + k0, bL + (32 * w + 16) * 64);
  gl_lds16(bS3 + k0, bL + (32 * w + 24) * 64);
}

__device__ __forceinline__ void gemm_mainloop_p(
    const u16* aS0, const u16* aS1, const u16* aS2, const u16* aS3,
    const u16* bS0, const u16* bS1, const u16* bS2, const u16* bS3,
    int K, u16* aL0, u16* bL0, u16* aL1, u16* bL1, f32x4 acc[4][4]) {
  const int t = threadIdx.x;
  const int w = t >> 6, lane = t & 63;
  const int wm = (w >> 1) * 64, wn = (w & 1) * 64;
  const int lr = lane & 15, lg = lane >> 4;
  const int T = K >> 6;
  stage8(aS0, aS1, aS2, aS3, bS0, bS1, bS2, bS3, 0, aL0, bL0, w);
  __syncthreads();
  for (int tt = 0; tt < T; ++tt) {
    u16* aC = (tt & 1) ? aL1 : aL0;
    u16* bC = (tt & 1) ? bL1 : bL0;
    if (tt + 1 < T) {
      u16* aN = (tt & 1) ? aL0 : aL1;
      u16* bN = (tt & 1) ? bL0 : bL1;
      stage8(aS0, aS1, aS2, aS3, bS0, bS1, bS2, bS3, (tt + 1) << 6, aN, bN, w);
    }
    __builtin_amdgcn_s_setprio(1);
#pragma unroll
    for (int kk = 0; kk < 2; ++kk) {
      bf16x8 af[4], bfr[4];
#pragma unroll
      for (int i = 0; i < 4; ++i) {
        int ra = wm + i * 16 + lr;
        af[i] = *reinterpret_cast<const bf16x8*>(aC + ra * 64 + (((kk * 4 + lg) ^ (ra & 7)) << 3));
        int rb = wn + i * 16 + lr;
        bfr[i] = *reinterpret_cast<const bf16x8*>(bC + rb * 64 + (((kk * 4 + lg) ^ (rb & 7)) << 3));
      }
#pragma unroll
      for (int mi = 0; mi < 4; ++mi)
#pragma unroll
        for (int ni = 0; ni < 4; ++ni)
          acc[mi][ni] = mfma16(af[mi], bfr[ni], acc[mi][ni]);
    }
    __builtin_amdgcn_s_setprio(0);
    __syncthreads();
  }
}

// ---------- 2-phase 64(M)x128(N) mainloop for the sparse GEMMs (more TLP) ----------
__device__ __forceinline__ void stage6(
    const u16* aS0, const u16* aS1,
    const u16* bS0, const u16* bS1, const u16* bS2, const u16* bS3,
    int k0, u16* aL, u16* bL, int w) {
  gl_lds16(aS0 + k0, aL + (16 * w + 0) * 64);
  gl_lds16(aS1 + k0, aL + (16 * w + 8) * 64);
  gl_lds16(bS0 + k0, bL + (32 * w + 0) * 64);
  gl_lds16(bS1 + k0, bL + (32 * w + 8) * 64);
  gl_lds16(bS2 + k0, bL + (32 * w + 16) * 64);
  gl_lds16(bS3 + k0, bL + (32 * w + 24) * 64);
}

__device__ __forceinline__ void gemm_mainloop64(
    const u16* aS0, const u16* aS1,
    const u16* bS0, const u16* bS1, const u16* bS2, const u16* bS3,
    int K, u16* aL0, u16* bL0, u16* aL1, u16* bL1, f32x4 acc[4][2]) {
  const int t = threadIdx.x;
  const int w = t >> 6, lane = t & 63;
  const int lr = lane & 15, lg = lane >> 4;
  const int T = K >> 6;
  stage6(aS0, aS1, bS0, bS1, bS2, bS3, 0, aL0, bL0, w);
  __syncthreads();
  for (int tt = 0; tt < T; ++tt) {
    u16* aC = (tt & 1) ? aL1 : aL0;
    u16* bC = (tt & 1) ? bL1 : bL0;
    if (tt + 1 < T) {
      u16* aN = (tt & 1) ? aL0 : aL1;
      u16* bN = (tt & 1) ? bL0 : bL1;
      stage6(aS0, aS1, bS0, bS1, bS2, bS3, (tt + 1) << 6, aN, bN, w);
    }
    __builtin_amdgcn_s_setprio(1);
#pragma unroll
    for (int kk = 0; kk < 2; ++kk) {
      bf16x8 af[4], bfr[2];
#pragma unroll
      for (int i = 0; i < 4; ++i) {
        int ra = i * 16 + lr;
        af[i] = *reinterpret_cast<const bf16x8*>(aC + ra * 64 + (((kk * 4 + lg) ^ (ra & 7)) << 3));
      }
#pragma unroll
      for (int j = 0; j < 2; ++j) {
        int rb = w * 32 + j * 16 + lr;
        bfr[j] = *reinterpret_cast<const bf16x8*>(bC + rb * 64 + (((kk * 4 + lg) ^ (rb & 7)) << 3));
      }
#pragma unroll
      for (int mi = 0; mi < 4; ++mi)
#pragma unroll
        for (int ni = 0; ni < 2; ++ni)
          acc[mi][ni] = mfma16(af[mi], bfr[ni], acc[mi][ni]);
    }
    __builtin_amdgcn_s_setprio(0);
    __syncthreads();
  }
}

// ---------- K + V^T GEMMs: kbuf[e][2048][1024]; vtbuf[e][2][1024 d][1024 tok] ----------
__global__ __launch_bounds__(256) void kv_gemm_kernel(
    const u16* __restrict__ xb, const u16* __restrict__ wb_qkv,
    const float* __restrict__ kb, const float* __restrict__ vb,
    u16* __restrict__ kbuf, u16* __restrict__ vtbuf) {
  __shared__ u16 lds[32768];
  int orig = blockIdx.x;                         // 2048, %8==0
  int wgid = (orig & 7) * 256 + (orig >> 3);     // XCD-bijective swizzle
  int e = wgid >> 8, r = wgid & 255;
  int ty = r >> 7, rr = r & 127;
  const int t = threadIdx.x, w = t >> 6, lane = t & 63;
  const int rloc = lane >> 3, cloc = lane & 7;
  const int sc8 = (cloc ^ rloc) * 8;
  const u16 *A, *B;
  int mblk, nblk;
  if (ty == 0) {            // K: A = xb tokens, B = kW rows
    mblk = rr >> 3; nblk = rr & 7;
    A = xb + (size_t)mblk * 128 * 1024;
    B = wb_qkv + (size_t)(e * 3 + 1) * 1048576 + (size_t)nblk * 128 * 1024;
  } else {                  // V^T: A = vW rows (d), B = xb tokens
    mblk = rr & 7; nblk = rr >> 3;
    A = wb_qkv + (size_t)(e * 3 + 2) * 1048576 + (size_t)mblk * 128 * 1024;
    B = xb + (size_t)nblk * 128 * 1024;
  }
  f32x4 acc[4][4];
#pragma unroll
  for (int i = 0; i < 4; ++i)
#pragma unroll
    for (int j = 0; j < 4; ++j) { f32x4 z = {0.f, 0.f, 0.f, 0.f}; acc[i][j] = z; }
  gemm_mainloop_p(
      A + (size_t)(32 * w + 0 + rloc) * 1024 + sc8, A + (size_t)(32 * w + 8 + rloc) * 1024 + sc8,
      A + (size_t)(32 * w + 16 + rloc) * 1024 + sc8, A + (size_t)(32 * w + 24 + rloc) * 1024 + sc8,
      B + (size_t)(32 * w + 0 + rloc) * 1024 + sc8, B + (size_t)(32 * w + 8 + rloc) * 1024 + sc8,
      B + (size_t)(32 * w + 16 + rloc) * 1024 + sc8, B + (size_t)(32 * w + 24 + rloc) * 1024 + sc8,
      1024, lds, lds + 8192, lds + 16384, lds + 24576, acc);
  const int wm = (w >> 1) * 64, wn = (w & 1) * 64;
  const int lr = lane & 15, lg = lane >> 4;
  if (ty == 0) {
    const float* bias = kb + (size_t)e * 1024 + nblk * 128;
    u16* Cb = kbuf + ((size_t)e * 2048 + (size_t)mblk * 128) * 1024 + nblk * 128;
#pragma unroll
    for (int ni = 0; ni < 4; ++ni) {
      int lcol = wn + ni * 16 + lr;
      float bv = bias[lcol];
#pragma unroll
      for (int mi = 0; mi < 4; ++mi)
#pragma unroll
        for (int rg = 0; rg < 4; ++rg) {
          int lrow = wm + mi * 16 + lg * 4 + rg;
          Cb[(size_t)lrow * 1024 + lcol] = f2bf(acc[mi][ni][rg] + bv);
        }
    }
  } else {
    const float* bias = vb + (size_t)e * 1024 + mblk * 128;   // bias along rows (d)
    int bb = nblk >> 3, nn = nblk & 7;
    u16* Cb = vtbuf + ((size_t)(e * 2 + bb) * 1024 + (size_t)mblk * 128) * 1024 + nn * 128;
#pragma unroll
    for (int ni = 0; ni < 4; ++ni) {
      int lcol = wn + ni * 16 + lr;
#pragma unroll
      for (int mi = 0; mi < 4; ++mi)
#pragma unroll
        for (int rg = 0; rg < 4; ++rg) {
          int lrow = wm + mi * 16 + lg * 4 + rg;
          Cb[(size_t)lrow * 1024 + lcol] = f2bf(acc[mi][ni][rg] + bias[lrow]);
        }
    }
  }
}

// ---------- Q gathered GEMM (64-row tiles): qc[p][pos][1024] ----------
__global__ __launch_bounds__(256) void q_gemm_kernel(
    const u16* __restrict__ xb, const u16* __restrict__ wb_qkv,
    const float* __restrict__ qb, const u32* __restrict__ tok_list,
    const u32* __restrict__ cnt, u16* __restrict__ qc) {
  __shared__ u16 lds[24576];   // a 2x4096, b 2x8192
  int nblk = blockIdx.x, mt = blockIdx.y, p = blockIdx.z;
  int c = (int)cnt[p];
  if (mt * 64 >= c) return;
  int e = p >> 1, b = p & 1;
  const int t = threadIdx.x, w = t >> 6, lane = t & 63;
  const int rloc = lane >> 3, cloc = lane & 7;
  const int sc8 = (cloc ^ rloc) * 8;
  const u32* tl = tok_list + p * 1024 + mt * 64 + 16 * w + rloc;
  int t0 = (int)(tl[0] & 1023), t1 = (int)(tl[8] & 1023);
  const u16* Ab = xb + (size_t)b * 1024 * 1024 + sc8;
  const u16* B = wb_qkv + (size_t)(e * 3) * 1048576 + (size_t)nblk * 128 * 1024;
  f32x4 acc[4][2];
#pragma unroll
  for (int i = 0; i < 4; ++i)
#pragma unroll
    for (int j = 0; j < 2; ++j) { f32x4 z = {0.f, 0.f, 0.f, 0.f}; acc[i][j] = z; }
  gemm_mainloop64(
      Ab + (size_t)t0 * 1024, Ab + (size_t)t1 * 1024,
      B + (size_t)(32 * w + 0 + rloc) * 1024 + sc8, B + (size_t)(32 * w + 8 + rloc) * 1024 + sc8,
      B + (size_t)(32 * w + 16 + rloc) * 1024 + sc8, B + (size_t)(32 * w + 24 + rloc) * 1024 + sc8,
      1024, lds, lds + 8192, lds + 4096, lds + 16384, acc);
  const int lr = lane & 15, lg = lane >> 4;
  const float* bias = qb + (size_t)e * 1024 + nblk * 128;
  u16* Cb = qc + ((size_t)p * 1024 + (size_t)mt * 64) * 1024 + nblk * 128;
#pragma unroll
  for (int ni = 0; ni < 2; ++ni) {
    int lcol = w * 32 + ni * 16 + lr;
    float bv = bias[lcol];
#pragma unroll
    for (int mi = 0; mi < 4; ++mi)
#pragma unroll
      for (int rg = 0; rg < 4; ++rg) {
        int lrow = mi * 16 + lg * 4 + rg;
        Cb[(size_t)lrow * 1024 + lcol] = f2bf(acc[mi][ni][rg] + bv);
      }
  }
}

// ---------- sparse flash attention: dbuf async K + Vt staging ----------
__global__ __launch_bounds__(256) void attn_kernel(
    const u16* __restrict__ qc, const u16* __restrict__ kbuf,
    const u16* __restrict__ vtbuf, const u32* __restrict__ cnt,
    u16* __restrict__ oc) {
  __shared__ u16 Kl[2][4096];    // [buf][tok 64][dh 64], source pre-swizzled
  __shared__ u16 Vtl[2][4096];   // [buf][dh 64][tok 64], source pre-swizzled
  __shared__ u16 Pl[4096];       // per-wave 1024
  int h = blockIdx.x;
  int p = blockIdx.y >> 3, lt = blockIdx.y & 7;
  int c = (int)cnt[p];
  if (lt * 64 >= c) return;
  int e = p >> 1, b = p & 1;
  const u16* Qb = qc + ((size_t)p * 1024 + (size_t)lt * 64) * 1024 + h * 64;
  const u16* Kg = kbuf + ((size_t)e * 2048 + (size_t)b * 1024) * 1024 + h * 64;
  const u16* Vtg = vtbuf + ((size_t)(e * 2 + b) * 1024 + (size_t)h * 64) * 1024;
  u16* Og = oc + ((size_t)p * 1024 + (size_t)lt * 64) * 1024 + h * 64;
  const int t = threadIdx.x, w = t >> 6, lane = t & 63;
  const int lr = lane & 15, lg = lane >> 4;
  const int rloc = lane >> 3, kc = lane & 7;

#define STAGE_ATTN(IT, KB, VB)                                                   \
  {                                                                              \
    int kv0_ = (IT) * 64;                                                        \
    _Pragma("unroll")                                                            \
    for (int r_ = 0; r_ < 2; ++r_) {                                             \
      int row_ = 16 * w + 8 * r_ + rloc;                                         \
      gl_lds16(Kg + (size_t)(kv0_ + row_) * 1024 + (kc ^ (row_ & 7)) * 8,        \
               (KB) + (16 * w + 8 * r_) * 64);                                   \
      gl_lds16(Vtg + (size_t)row_ * 1024 + kv0_ + (kc ^ (row_ & 7)) * 8,         \
               (VB) + (16 * w + 8 * r_) * 64);                                   \
    }                                                                            \
  }

  STAGE_ATTN(0, Kl[0], Vtl[0]);

  bf16x8 qa0 = *reinterpret_cast<const bf16x8*>(Qb + (size_t)(w * 16 + lr) * 1024 + lg * 8);
  bf16x8 qa1 = *reinterpret_cast<const bf16x8*>(Qb + (size_t)(w * 16 + lr) * 1024 + 32 + lg * 8);

  f32x4 oacc[4];
  float mrun[4], lsum[4];
#pragma unroll
  for (int i = 0; i < 4; ++i) {
    f32x4 z = {0.f, 0.f, 0.f, 0.f}; oacc[i] = z; mrun[i] = -3.4e38f; lsum[i] = 0.f;
  }
  __syncthreads();   // tile 0 resident

  for (int it = 0; it < 16; ++it) {
    const int cur = it & 1;
    const u16* Kc = Kl[cur];
    const u16* Vc = Vtl[cur];
    if (it + 1 < 16) STAGE_ATTN(it + 1, Kl[cur ^ 1], Vtl[cur ^ 1]);
    // ---- QK^T ----
    f32x4 sv[4];
    __builtin_amdgcn_s_setprio(1);
#pragma unroll
    for (int nt = 0; nt < 4; ++nt) {
      f32x4 z = {0.f, 0.f, 0.f, 0.f};
#pragma unroll
      for (int kk = 0; kk < 2; ++kk) {
        int rk = nt * 16 + lr;
        bf16x8 kf = *reinterpret_cast<const bf16x8*>(Kc + rk * 64 + (((kk * 4 + lg) ^ (rk & 7)) << 3));
        z = mfma16(kk ? qa1 : qa0, kf, z);
      }
      sv[nt] = z * 0.125f;
    }
    __builtin_amdgcn_s_setprio(0);
    // ---- online softmax ----
#pragma unroll
    for (int rg = 0; rg < 4; ++rg) {
      float tm = fmaxf(fmaxf(sv[0][rg], sv[1][rg]), fmaxf(sv[2][rg], sv[3][rg]));
#pragma unroll
      for (int mm = 1; mm < 16; mm <<= 1) tm = fmaxf(tm, __shfl_xor(tm, mm));
      float mn = fmaxf(mrun[rg], tm);
      float al = __expf(mrun[rg] - mn);
      mrun[rg] = mn;
      lsum[rg] *= al;
#pragma unroll
      for (int nt = 0; nt < 4; ++nt) oacc[nt][rg] *= al;
    }
#pragma unroll
    for (int nt = 0; nt < 4; ++nt) {
#pragma unroll
      for (int rg = 0; rg < 4; ++rg) {
        float pv = __expf(sv[nt][rg] - mrun[rg]);
        lsum[rg] += pv;
        int prow = lg * 4 + rg;
        Pl[w * 1024 + prow * 64 + ((nt * 16 + lr) ^ ((prow & 7) << 3))] = f2bf(pv);
      }
    }
    // ---- PV ----
    __builtin_amdgcn_s_setprio(1);
#pragma unroll
    for (int kk = 0; kk < 2; ++kk) {
      bf16x8 pf = *reinterpret_cast<const bf16x8*>(
          Pl + w * 1024 + lr * 64 + (((kk * 4 + lg) ^ (lr & 7)) << 3));
#pragma unroll
      for (int nt = 0; nt < 4; ++nt) {
        int rv = nt * 16 + lr;
        bf16x8 vf = *reinterpret_cast<const bf16x8*>(Vc + rv * 64 + (((kk * 4 + lg) ^ (rv & 7)) << 3));
        oacc[nt] = mfma16(pf, vf, oacc[nt]);
      }
    }
    __builtin_amdgcn_s_setprio(0);
    __syncthreads();   // drains prefetch vmcnt; buffers swap safely
  }
#pragma unroll
  for (int rg = 0; rg < 4; ++rg) {
#pragma unroll
    for (int mm = 1; mm < 16; mm <<= 1) lsum[rg] += __shfl_xor(lsum[rg], mm);
    float inv = 1.0f / lsum[rg];
#pragma unroll
    for (int nt = 0; nt < 4; ++nt)
      Og[(size_t)(w * 16 + lg * 4 + rg) * 1024 + nt * 16 + lr] = f2bf(oacc[nt][rg] * inv);
  }
#undef STAGE_ATTN
}

// ---------- output projection (64-row tiles, compact rows, plain stores) ----------
__global__ __launch_bounds__(256) void oproj_kernel(
    const u16* __restrict__ oc, const u16* __restrict__ wb_o,
    const u32* __restrict__ cnt, float* __restrict__ projc) {
  __shared__ u16 lds[24576];
  int nblk = blockIdx.x, mt = blockIdx.y, p = blockIdx.z;
  int c = (int)cnt[p];
  if (mt * 64 >= c) return;
  int e = p >> 1;
  const int t = threadIdx.x, w = t >> 6, lane = t & 63;
  const int rloc = lane >> 3, cloc = lane & 7;
  const int sc8 = (cloc ^ rloc) * 8;
  const u16* A = oc + ((size_t)p * 1024 + (size_t)mt * 64) * 1024;
  const u16* B = wb_o + (size_t)e * 1048576 + (size_t)nblk * 128 * 1024;
  f32x4 acc[4][2];
#pragma unroll
  for (int i = 0; i < 4; ++i)
#pragma unroll
    for (int j = 0; j < 2; ++j) { f32x4 z = {0.f, 0.f, 0.f, 0.f}; acc[i][j] = z; }
  gemm_mainloop64(
      A + (size_t)(16 * w + 0 + rloc) * 1024 + sc8, A + (size_t)(16 * w + 8 + rloc) * 1024 + sc8,
      B + (size_t)(32 * w + 0 + rloc) * 1024 + sc8, B + (size_t)(32 * w + 8 + rloc) * 1024 + sc8,
      B + (size_t)(32 * w + 16 + rloc) * 1024 + sc8, B + (size_t)(32 * w + 24 + rloc) * 1024 + sc8,
      1024, lds, lds + 8192, lds + 4096, lds + 16384, acc);
  const int lr = lane & 15, lg = lane >> 4;
  float* Pb = projc + ((size_t)p * 1024 + (size_t)mt * 64) * 1024 + nblk * 128;
#pragma unroll
  for (int mi = 0; mi < 4; ++mi)
#pragma unroll
    for (int rg = 0; rg < 4; ++rg) {
      int lrow = mi * 16 + lg * 4 + rg;
#pragma unroll
      for (int ni = 0; ni < 2; ++ni) {
        int lcol = w * 32 + ni * 16 + lr;
        Pb[(size_t)lrow * 1024 + lcol] = acc[mi][ni][rg];
      }
    }
}

// ---------- final merge: out[tok] = g1*(projc1+ob1) + g2*(projc2+ob2) ----------
__global__ __launch_bounds__(256) void merge_out(
    const float* __restrict__ projc, const float* __restrict__ ob,
    const float* __restrict__ gate_list, const u32* __restrict__ inv,
    float* __restrict__ out) {
  int tok = blockIdx.x;
  int c4 = threadIdx.x * 4;
  u32 i1 = inv[tok * 2], i2 = inv[tok * 2 + 1];
  int idx1 = (int)(i1 >> 10) * 1024 + (int)(i1 & 1023);
  int idx2 = (int)(i2 >> 10) * 1024 + (int)(i2 & 1023);
  float g1 = gate_list[idx1], g2 = gate_list[idx2];
  int e1 = (int)(i1 >> 11), e2 = (int)(i2 >> 11);
  float4 a = *reinterpret_cast<const float4*>(projc + (size_t)idx1 * 1024 + c4);
  float4 bvec = *reinterpret_cast<const float4*>(projc + (size_t)idx2 * 1024 + c4);
  float4 o1 = *reinterpret_cast<const float4*>(ob + (size_t)e1 * 1024 + c4);
  float4 o2 = *reinterpret_cast<const float4*>(ob + (size_t)e2 * 1024 + c4);
  float4 r;
  r.x = g1 * (a.x + o1.x) + g2 * (bvec.x + o2.x);
  r.y = g1 * (a.y + o1.y) + g2 * (bvec.y + o2.y);
  r.z = g1 * (a.z + o1.z) + g2 * (bvec.z + o2.z);
  r.w = g1 * (a.w + o1.w) + g2 * (bvec.w + o2.w);
  *reinterpret_cast<float4*>(out + (size_t)tok * 1024 + c4) = r;
}

// ---------- host launcher ----------
extern "C" void kernel_launch(void* const* d_in, const int* in_sizes, int n_in,
                              void* d_out, int out_size, void* d_ws, size_t ws_size,
                              hipStream_t stream) {
  const float* x    = (const float*)d_in[0];
  const float* rW1  = (const float*)d_in[1];
  const float* rb1  = (const float*)d_in[2];
  const float* ln_g = (const float*)d_in[3];
  const float* ln_b = (const float*)d_in[4];
  const float* rW2  = (const float*)d_in[5];
  const float* rb2  = (const float*)d_in[6];
  const float* qW   = (const float*)d_in[7];
  const float* qb   = (const float*)d_in[8];
  const float* kW   = (const float*)d_in[9];
  const float* kb   = (const float*)d_in[10];
  const float* vW   = (const float*)d_in[11];
  const float* vb   = (const float*)d_in[12];
  const float* oW   = (const float*)d_in[13];
  const float* ob   = (const float*)d_in[14];
  float* out = (float*)d_out;

  const size_t need = 50331648ull + 16777216ull + 67108864ull + 33554432ull +
                      33554432ull + 4194304ull + 147520ull;
  if (ws_size < need) return;
  char* pp = (char*)d_ws;
  u16* wb_qkv = (u16*)pp; pp += 50331648ull;   // [8][3][1024][1024]
  u16* wb_o   = (u16*)pp; pp += 16777216ull;   // [8][1024][1024]
  u16* kbuf   = (u16*)pp; pp += 33554432ull;   // [8][2048][1024]
  u16* vtbuf  = (u16*)pp; pp += 33554432ull;   // [8][2][1024 d][1024 tok]
  u16* qc     = (u16*)pp; pp += 33554432ull;   // [16][1024][1024]
  u16* oc     = (u16*)pp; pp += 33554432ull;   // [16][1024][1024]
  u16* xb     = (u16*)pp; pp += 4194304ull;    // [2048][1024]
  u32* lists  = (u32*)pp;
  u32* tok_list    = lists;                    // 16384
  float* gate_list = (float*)(lists + 16384);  // 16384
  u32* cnt         = lists + 32768;            // 16
  u32* inv         = lists + 32784;            // 4096
  float* hbuf  = (float*)qc;                   // alias (dead before qc written)
  float* projc = (float*)kbuf;                 // alias kbuf+vtbuf (dead after attn)

  cvt_x_kernel<<<dim3(2048), dim3(256), 0, stream>>>(x, xb, lists);
  cvt_w_kernel<<<dim3(2048), dim3(256), 0, stream>>>(qW, kW, vW, oW, wb_qkv, wb_o);
  router_gemm1<<<dim3(32, 8), dim3(256), 0, stream>>>(x, rW1, rb1, hbuf);
  router_finish<<<dim3(2048), dim3(64), 0, stream>>>(hbuf, ln_g, ln_b, rW2, rb2,
                                                     tok_list, gate_list, cnt, inv);
  kv_gemm_kernel<<<dim3(2048), dim3(256), 0, stream>>>(xb, wb_qkv, kb, vb, kbuf, vtbuf);
  q_gemm_kernel<<<dim3(8, 16, 16), dim3(256), 0, stream>>>(xb, wb_qkv, qb, tok_list, cnt, qc);
  attn_kernel<<<dim3(16, 128), dim3(256), 0, stream>>>(qc, kbuf, vtbuf, cnt, oc);
  oproj_kernel<<<dim3(8, 16, 16), dim3(256), 0, stream>>>(oc, wb_o, cnt, projc);
  merge_out<<<dim3(2048), dim3(256), 0, stream>>>(projc, ob, gate_list, inv, out);
}